// Round 1
// baseline (2135.612 us; speedup 1.0000x reference)
//
#include <hip/hip_runtime.h>

#define N_  16
#define C_  256
#define H_  96
#define W_  96
#define HW_ 9216
#define QK_ 4

// ---------------------------------------------------------------------------
// K1: Q/K projection  (x[n,c,h,w] -> Q[n,4,h,w], K[n,4,h,w])
// ---------------------------------------------------------------------------
__global__ __launch_bounds__(256) void ccca_qk(
    const float* __restrict__ x, const float* __restrict__ Wq,
    const float* __restrict__ Wk, float* __restrict__ Qo, float* __restrict__ Ko)
{
    __shared__ float sWq[QK_ * C_];
    __shared__ float sWk[QK_ * C_];
    int t = threadIdx.x;
    for (int i = t; i < QK_ * C_; i += 256) { sWq[i] = Wq[i]; sWk[i] = Wk[i]; }
    __syncthreads();
    int n = blockIdx.x / 36;
    int p = (blockIdx.x % 36) * 256 + t;       // pixel within plane
    const float* xp = x + (size_t)n * C_ * HW_ + p;
    float qa[QK_] = {0.f, 0.f, 0.f, 0.f};
    float ka[QK_] = {0.f, 0.f, 0.f, 0.f};
    for (int c = 0; c < C_; ++c) {
        float v = xp[(size_t)c * HW_];
        #pragma unroll
        for (int q = 0; q < QK_; ++q) {
            qa[q] = fmaf(v, sWq[q * C_ + c], qa[q]);
            ka[q] = fmaf(v, sWk[q * C_ + c], ka[q]);
        }
    }
    size_t base = (size_t)n * QK_ * HW_ + p;
    #pragma unroll
    for (int q = 0; q < QK_; ++q) { Qo[base + q * HW_] = qa[q]; Ko[base + q * HW_] = ka[q]; }
}

// ---------------------------------------------------------------------------
// K2: row attention. Per (n,h): A[w][v] = softmax_v(sum_q Q[q,w]K[q,v]),
//     T1[o][w] = sum_v x[n,o,h,v] * A[w][v]   -> writes d_out (init)
// ---------------------------------------------------------------------------
__global__ __launch_bounds__(256) void ccca_row(
    const float* __restrict__ x, const float* __restrict__ Qw,
    const float* __restrict__ Kw, float* __restrict__ out)
{
    __shared__ float sQ[QK_][W_];
    __shared__ float sK[QK_][W_];
    __shared__ float A[W_][W_ + 1];
    __shared__ float Xs[64][W_ + 1];
    int t = threadIdx.x;
    int n = blockIdx.x / H_;
    int h = blockIdx.x % H_;
    for (int i = t; i < QK_ * W_; i += 256) {
        int q = i / W_, w = i % W_;
        size_t off = ((size_t)n * QK_ + q) * HW_ + h * W_ + w;
        sQ[q][w] = Qw[off];
        sK[q][w] = Kw[off];
    }
    __syncthreads();
    for (int i = t; i < W_ * W_; i += 256) {
        int w = i / W_, v = i % W_;
        float s = 0.f;
        #pragma unroll
        for (int q = 0; q < QK_; ++q) s = fmaf(sQ[q][w], sK[q][v], s);
        A[w][v] = s;
    }
    __syncthreads();
    if (t < W_) {                      // softmax over v for row w = t
        float m = -1e30f;
        for (int v = 0; v < W_; ++v) m = fmaxf(m, A[t][v]);
        float sum = 0.f;
        for (int v = 0; v < W_; ++v) { float e = __expf(A[t][v] - m); A[t][v] = e; sum += e; }
        float inv = 1.f / sum;
        for (int v = 0; v < W_; ++v) A[t][v] *= inv;
    }
    __syncthreads();
    int to = t >> 4, tw = t & 15;      // 16x16 threads: 4 o's x 6 w's each
    for (int ot = 0; ot < 4; ++ot) {
        for (int i = t; i < 64 * W_ / 4; i += 256) {
            int f = i * 4;
            int o = f / W_, v = f % W_;
            float4 val = *(const float4*)(x + (((size_t)n * C_ + ot * 64 + o) * H_ + h) * W_ + v);
            Xs[o][v] = val.x; Xs[o][v + 1] = val.y; Xs[o][v + 2] = val.z; Xs[o][v + 3] = val.w;
        }
        __syncthreads();
        float acc[4][6];
        #pragma unroll
        for (int i = 0; i < 4; ++i)
            #pragma unroll
            for (int j = 0; j < 6; ++j) acc[i][j] = 0.f;
        for (int v = 0; v < W_; ++v) {
            float xr[4], ar[6];
            #pragma unroll
            for (int i = 0; i < 4; ++i) xr[i] = Xs[to * 4 + i][v];
            #pragma unroll
            for (int j = 0; j < 6; ++j) ar[j] = A[tw * 6 + j][v];
            #pragma unroll
            for (int i = 0; i < 4; ++i)
                #pragma unroll
                for (int j = 0; j < 6; ++j) acc[i][j] = fmaf(xr[i], ar[j], acc[i][j]);
        }
        #pragma unroll
        for (int i = 0; i < 4; ++i) {
            size_t ob = (((size_t)n * C_ + ot * 64 + to * 4 + i) * H_ + h) * W_ + tw * 6;
            #pragma unroll
            for (int j = 0; j < 6; ++j) out[ob + j] = acc[i][j];
        }
        __syncthreads();
    }
}

// ---------------------------------------------------------------------------
// K3: col attention. Per (n,w): A[h][g] = softmax_g(sum_q Q[q,h]K[q,g]),
//     T2[o][h] = sum_g x[n,o,g,w] * A[h][g]   -> accumulates += into d_out
// ---------------------------------------------------------------------------
__global__ __launch_bounds__(256) void ccca_col(
    const float* __restrict__ x, const float* __restrict__ Qw,
    const float* __restrict__ Kw, float* __restrict__ out)
{
    __shared__ float sQ[QK_][H_];
    __shared__ float sK[QK_][H_];
    __shared__ float A[H_][H_ + 1];
    __shared__ float Xc[64][H_ + 1];
    int t = threadIdx.x;
    int n = blockIdx.x / W_;
    int w = blockIdx.x % W_;
    for (int i = t; i < QK_ * H_; i += 256) {
        int q = i / H_, hh = i % H_;
        size_t off = ((size_t)n * QK_ + q) * HW_ + hh * W_ + w;
        sQ[q][hh] = Qw[off];
        sK[q][hh] = Kw[off];
    }
    __syncthreads();
    for (int i = t; i < H_ * H_; i += 256) {
        int hh = i / H_, g = i % H_;
        float s = 0.f;
        #pragma unroll
        for (int q = 0; q < QK_; ++q) s = fmaf(sQ[q][hh], sK[q][g], s);
        A[hh][g] = s;
    }
    __syncthreads();
    if (t < H_) {                      // softmax over g for row h = t
        float m = -1e30f;
        for (int g = 0; g < H_; ++g) m = fmaxf(m, A[t][g]);
        float sum = 0.f;
        for (int g = 0; g < H_; ++g) { float e = __expf(A[t][g] - m); A[t][g] = e; sum += e; }
        float inv = 1.f / sum;
        for (int g = 0; g < H_; ++g) A[t][g] *= inv;
    }
    __syncthreads();
    int to = t >> 4, th = t & 15;
    for (int ot = 0; ot < 4; ++ot) {
        for (int i = t; i < 64 * H_; i += 256) {   // strided gather (known slow; measuring)
            int o = i / H_, g = i % H_;
            Xc[o][g] = x[(((size_t)n * C_ + ot * 64 + o) * H_ + g) * W_ + w];
        }
        __syncthreads();
        float acc[4][6];
        #pragma unroll
        for (int i = 0; i < 4; ++i)
            #pragma unroll
            for (int j = 0; j < 6; ++j) acc[i][j] = 0.f;
        for (int g = 0; g < H_; ++g) {
            float xr[4], ar[6];
            #pragma unroll
            for (int i = 0; i < 4; ++i) xr[i] = Xc[to * 4 + i][g];
            #pragma unroll
            for (int j = 0; j < 6; ++j) ar[j] = A[th * 6 + j][g];
            #pragma unroll
            for (int i = 0; i < 4; ++i)
                #pragma unroll
                for (int j = 0; j < 6; ++j) acc[i][j] = fmaf(xr[i], ar[j], acc[i][j]);
        }
        #pragma unroll
        for (int i = 0; i < 4; ++i)
            #pragma unroll
            for (int j = 0; j < 6; ++j) {
                size_t ob = (((size_t)n * C_ + ot * 64 + to * 4 + i) * H_ + th * 6 + j) * W_ + w;
                out[ob] += acc[i][j];
            }
        __syncthreads();
    }
}

// ---------------------------------------------------------------------------
// K4: in-place channel mix: out[:,p] = Wv @ out[:,p], per 64-pixel tile
// ---------------------------------------------------------------------------
__global__ __launch_bounds__(256) void ccca_wv(
    const float* __restrict__ Wv, float* __restrict__ out)
{
    __shared__ float Ts[C_][64];
    int t = threadIdx.x;
    int n = blockIdx.x / 144;
    int p0 = (blockIdx.x % 144) * 64;
    float* base = out + (size_t)n * C_ * HW_ + p0;
    for (int i = t; i < C_ * 16; i += 256) {
        int o = i >> 4, p4 = (i & 15) << 2;
        *(float4*)&Ts[o][p4] = *(const float4*)(base + (size_t)o * HW_ + p4);
    }
    __syncthreads();
    int cb = t >> 4, pb = t & 15;      // 16 channels x 4 pixels per thread
    float acc[16][4];
    #pragma unroll
    for (int j = 0; j < 16; ++j)
        #pragma unroll
        for (int p = 0; p < 4; ++p) acc[j][p] = 0.f;
    for (int o = 0; o < C_; o += 4) {
        float tvv[4][4];
        #pragma unroll
        for (int k = 0; k < 4; ++k) {
            float4 q = *(float4*)&Ts[o + k][pb * 4];
            tvv[k][0] = q.x; tvv[k][1] = q.y; tvv[k][2] = q.z; tvv[k][3] = q.w;
        }
        #pragma unroll
        for (int j = 0; j < 16; ++j) {
            float4 wv = *(const float4*)(Wv + (size_t)(cb * 16 + j) * C_ + o);
            float wvv[4] = {wv.x, wv.y, wv.z, wv.w};
            #pragma unroll
            for (int k = 0; k < 4; ++k)
                #pragma unroll
                for (int p = 0; p < 4; ++p)
                    acc[j][p] = fmaf(wvv[k], tvv[k][p], acc[j][p]);
        }
    }
    #pragma unroll
    for (int j = 0; j < 16; ++j) {
        float4 r; r.x = acc[j][0]; r.y = acc[j][1]; r.z = acc[j][2]; r.w = acc[j][3];
        *(float4*)(base + (size_t)(cb * 16 + j) * HW_ + pb * 4) = r;
    }
}

// ---------------------------------------------------------------------------
// K5: avg & max pool over HxW per (n,c). Template arg encodes ws_size bucket
//     so rocprof dispatch names report it (0:<8MB 1:<64 2:<160 3:<256 4:<512 5:>=512)
// ---------------------------------------------------------------------------
template<int WSB>
__global__ __launch_bounds__(256) void ccca_pool(
    const float* __restrict__ out, float* __restrict__ avg, float* __restrict__ mx)
{
    int nc = blockIdx.x;
    const float* p = out + (size_t)nc * HW_;
    int t = threadIdx.x;
    float s = 0.f, m = -1e30f;
    for (int i = t; i < HW_; i += 256) { float v = p[i]; s += v; m = fmaxf(m, v); }
    #pragma unroll
    for (int off = 32; off > 0; off >>= 1) {
        s += __shfl_down(s, off);
        m = fmaxf(m, __shfl_down(m, off));
    }
    __shared__ float ss[4], smx[4];
    int wv = t >> 6;
    if ((t & 63) == 0) { ss[wv] = s; smx[wv] = m; }
    __syncthreads();
    if (t == 0) {
        s = ss[0] + ss[1] + ss[2] + ss[3];
        m = fmaxf(fmaxf(smx[0], smx[1]), fmaxf(smx[2], smx[3]));
        avg[nc] = s * (1.f / 9216.f);
        mx[nc] = m;
    }
}

// ---------------------------------------------------------------------------
// K6: SE gate: sigmoid( relu(avg@W1^T)@W2^T + relu(max@W1^T)@W2^T )
// ---------------------------------------------------------------------------
__global__ __launch_bounds__(256) void ccca_gate(
    const float* __restrict__ avg, const float* __restrict__ mx,
    const float* __restrict__ W1, const float* __restrict__ W2,
    float* __restrict__ gate)
{
    __shared__ float sa[C_], sm[C_], hs[C_];
    int n = blockIdx.x, t = threadIdx.x;
    sa[t] = avg[n * C_ + t];
    sm[t] = mx[n * C_ + t];
    __syncthreads();
    const float* w1r = W1 + (size_t)t * C_;
    float aa = 0.f, am = 0.f;
    for (int i = 0; i < C_; ++i) { float wv = w1r[i]; aa = fmaf(wv, sa[i], aa); am = fmaf(wv, sm[i], am); }
    hs[t] = fmaxf(aa, 0.f) + fmaxf(am, 0.f);
    __syncthreads();
    const float* w2r = W2 + (size_t)t * C_;
    float g = 0.f;
    for (int i = 0; i < C_; ++i) g = fmaf(w2r[i], hs[i], g);
    gate[n * C_ + t] = 1.f / (1.f + __expf(-g));
}

// ---------------------------------------------------------------------------
// K7: final: out = gama * gate[n,c] * out + x   (elementwise, float4)
// ---------------------------------------------------------------------------
template<int WSB>
__global__ __launch_bounds__(256) void ccca_final(
    const float* __restrict__ x, const float* __restrict__ gate,
    const float* __restrict__ gama, float* __restrict__ out)
{
    float g0 = gama[0];
    const size_t total = (size_t)N_ * C_ * HW_ / 4;
    for (size_t i = (size_t)blockIdx.x * 256 + threadIdx.x; i < total; i += (size_t)gridDim.x * 256) {
        float4 o = ((const float4*)out)[i];
        float4 xv = ((const float4*)x)[i];
        size_t nc = (i * 4) / HW_;
        float sc = g0 * gate[nc];
        o.x = fmaf(sc, o.x, xv.x);
        o.y = fmaf(sc, o.y, xv.y);
        o.z = fmaf(sc, o.z, xv.z);
        o.w = fmaf(sc, o.w, xv.w);
        ((float4*)out)[i] = o;
    }
}

// ---------------------------------------------------------------------------
extern "C" void kernel_launch(void* const* d_in, const int* in_sizes, int n_in,
                              void* d_out, int out_size, void* d_ws, size_t ws_size,
                              hipStream_t stream)
{
    const float* x    = (const float*)d_in[0];
    const float* Wq   = (const float*)d_in[1];
    const float* Wk   = (const float*)d_in[2];
    const float* Wv   = (const float*)d_in[3];
    const float* W1   = (const float*)d_in[4];
    const float* W2   = (const float*)d_in[5];
    const float* gama = (const float*)d_in[6];
    float* out = (float*)d_out;
    float* ws  = (float*)d_ws;

    const size_t QSZ = (size_t)N_ * QK_ * HW_;   // 589824 floats
    float* Qb   = ws;
    float* Kb   = ws + QSZ;
    float* avg  = ws + 2 * QSZ;
    float* mx   = avg + N_ * C_;
    float* gate = mx + N_ * C_;

    ccca_qk  <<<N_ * 36, 256, 0, stream>>>(x, Wq, Wk, Qb, Kb);
    ccca_row <<<N_ * H_, 256, 0, stream>>>(x, Qb, Kb, out);
    ccca_col <<<N_ * W_, 256, 0, stream>>>(x, Qb, Kb, out);
    ccca_wv  <<<N_ * 144, 256, 0, stream>>>(Wv, out);

    int wsb;
    const size_t MB = 1024u * 1024u;
    if      (ws_size <   8 * MB) wsb = 0;
    else if (ws_size <  64 * MB) wsb = 1;
    else if (ws_size < 160 * MB) wsb = 2;
    else if (ws_size < 256 * MB) wsb = 3;
    else if (ws_size < 512 * MB) wsb = 4;
    else                         wsb = 5;

    switch (wsb) {
        case 0: ccca_pool<0><<<N_ * C_, 256, 0, stream>>>(out, avg, mx); break;
        case 1: ccca_pool<1><<<N_ * C_, 256, 0, stream>>>(out, avg, mx); break;
        case 2: ccca_pool<2><<<N_ * C_, 256, 0, stream>>>(out, avg, mx); break;
        case 3: ccca_pool<3><<<N_ * C_, 256, 0, stream>>>(out, avg, mx); break;
        case 4: ccca_pool<4><<<N_ * C_, 256, 0, stream>>>(out, avg, mx); break;
        default: ccca_pool<5><<<N_ * C_, 256, 0, stream>>>(out, avg, mx); break;
    }

    ccca_gate<<<N_, 256, 0, stream>>>(avg, mx, W1, W2, gate);

    switch (wsb) {
        case 0: ccca_final<0><<<2048, 256, 0, stream>>>(x, gate, gama, out); break;
        case 1: ccca_final<1><<<2048, 256, 0, stream>>>(x, gate, gama, out); break;
        case 2: ccca_final<2><<<2048, 256, 0, stream>>>(x, gate, gama, out); break;
        case 3: ccca_final<3><<<2048, 256, 0, stream>>>(x, gate, gama, out); break;
        case 4: ccca_final<4><<<2048, 256, 0, stream>>>(x, gate, gama, out); break;
        default: ccca_final<5><<<2048, 256, 0, stream>>>(x, gate, gama, out); break;
    }
}

// Round 2
// 984.488 us; speedup vs baseline: 2.1693x; 2.1693x over previous
//
#include <hip/hip_runtime.h>
#include <hip/hip_fp16.h>

#define N_  16
#define C_  256
#define H_  96
#define W_  96
#define HW_ 9216
#define QK_ 4

struct alignas(8) h4 { __half2 a, b; };

__device__ inline void h4_unpack(h4 v, float* f) {
    float2 lo = __half22float2(v.a), hi = __half22float2(v.b);
    f[0] = lo.x; f[1] = lo.y; f[2] = hi.x; f[3] = hi.y;
}
__device__ inline h4 h4_pack(float a, float b, float c, float d) {
    h4 r; r.a = __floats2half2_rn(a, b); r.b = __floats2half2_rn(c, d); return r;
}

// ===========================================================================
// FAST PATH
// ===========================================================================

// K1: per (n,h): stage x row -> Q,K -> row softmax -> T1 -> Tb[n][px][c] fp16
//     Also emits xTb[n][w][h][c] (transposed copy for col kernel).
template<int WSB>
__global__ __launch_bounds__(256) void ccca_rowf(
    const float* __restrict__ x, const float* __restrict__ Wq, const float* __restrict__ Wk,
    float* __restrict__ Qs, float* __restrict__ Ks,
    __half* __restrict__ xTb, __half* __restrict__ Tb)
{
    __shared__ __half XsT[W_][C_ + 4];   // [w][c]
    __shared__ __half Ah[W_][100];
    __shared__ float sQ[QK_][W_];
    __shared__ float sK[QK_][W_];
    int t = threadIdx.x;
    int n = blockIdx.x / H_, h = blockIdx.x % H_;
    const float* xb = x + (size_t)n * C_ * HW_ + (size_t)h * W_;
    for (int i = t; i < C_ * (W_ / 4); i += 256) {
        int c = i / 24, s4 = (i % 24) * 4;
        float4 v = *(const float4*)(xb + (size_t)c * HW_ + s4);
        XsT[s4    ][c] = __float2half(v.x);
        XsT[s4 + 1][c] = __float2half(v.y);
        XsT[s4 + 2][c] = __float2half(v.z);
        XsT[s4 + 3][c] = __float2half(v.w);
    }
    __syncthreads();
    // transposed copy out: xTb[n][w][h][c]
    {
        __half* xd = xTb + ((size_t)n * W_ * H_ + h) * C_;
        for (int i = t; i < W_ * (C_ / 4); i += 256) {
            int w = i / 64, s = (i % 64) * 4;
            *(h4*)(xd + (size_t)w * H_ * C_ + s) = *(const h4*)&XsT[w][s];
        }
    }
    // Q,K projection for this row (also persisted for col kernel)
    for (int i = t; i < 2 * QK_ * W_; i += 256) {
        int sel = i / (QK_ * W_), r = i % (QK_ * W_);
        int q = r / W_, w = r % W_;
        const float* wr = (sel ? Wk : Wq) + q * C_;
        float s = 0.f;
        for (int c = 0; c < C_; ++c) s = fmaf(wr[c], __half2float(XsT[w][c]), s);
        if (sel) { sK[q][w] = s; Ks[(((size_t)n * QK_ + q) * H_ + h) * W_ + w] = s; }
        else     { sQ[q][w] = s; Qs[(((size_t)n * QK_ + q) * H_ + h) * W_ + w] = s; }
    }
    __syncthreads();
    for (int i = t; i < W_ * W_; i += 256) {
        int w = i / W_, v = i % W_;
        float s = 0.f;
        #pragma unroll
        for (int q = 0; q < QK_; ++q) s = fmaf(sQ[q][w], sK[q][v], s);
        Ah[w][v] = __float2half(s);
    }
    __syncthreads();
    if (t < W_) {
        float m = -1e30f;
        for (int v = 0; v < W_; ++v) m = fmaxf(m, __half2float(Ah[t][v]));
        float sum = 0.f;
        for (int v = 0; v < W_; ++v) {
            float e = __expf(__half2float(Ah[t][v]) - m);
            sum += e;
            Ah[t][v] = __float2half(e);
        }
        float inv = 1.f / sum;
        for (int v = 0; v < W_; ++v)
            Ah[t][v] = __float2half(__half2float(Ah[t][v]) * inv);
    }
    __syncthreads();
    int to = t >> 4, tw = t & 15;
    __half* Tn = Tb + ((size_t)n * H_ + h) * W_ * C_;
    for (int ot = 0; ot < 4; ++ot) {
        int ob = ot * 64 + to * 4;
        float acc[4][6];
        #pragma unroll
        for (int i = 0; i < 4; ++i)
            #pragma unroll
            for (int j = 0; j < 6; ++j) acc[i][j] = 0.f;
        for (int v = 0; v < W_; ++v) {
            float xr[4];
            h4_unpack(*(const h4*)&XsT[v][ob], xr);
            float ar[6];
            #pragma unroll
            for (int j = 0; j < 6; ++j) ar[j] = __half2float(Ah[tw * 6 + j][v]);
            #pragma unroll
            for (int i = 0; i < 4; ++i)
                #pragma unroll
                for (int j = 0; j < 6; ++j) acc[i][j] = fmaf(xr[i], ar[j], acc[i][j]);
        }
        #pragma unroll
        for (int j = 0; j < 6; ++j) {
            int w = tw * 6 + j;
            *(h4*)(Tn + (size_t)w * C_ + ob) =
                h4_pack(acc[0][j], acc[1][j], acc[2][j], acc[3][j]);
        }
    }
}

// K2: per (n,w): col attention from persisted Q,K; values from xTb (coalesced);
//     RMW-accumulates T2 into Tb as 8B segments.
template<int WSB>
__global__ __launch_bounds__(256) void ccca_col2(
    const float* __restrict__ Qs, const float* __restrict__ Ks,
    const __half* __restrict__ xTb, __half* __restrict__ Tb)
{
    __shared__ __half XTw[H_][C_ + 4];   // [g][c]
    __shared__ __half Ah[H_][100];
    __shared__ float sQ[QK_][H_];
    __shared__ float sK[QK_][H_];
    int t = threadIdx.x;
    int n = blockIdx.x / W_, w = blockIdx.x % W_;
    for (int i = t; i < 2 * QK_ * H_; i += 256) {
        int sel = i / (QK_ * H_), r = i % (QK_ * H_);
        int q = r / H_, g = r % H_;
        float v = (sel ? Ks : Qs)[(((size_t)n * QK_ + q) * H_ + g) * W_ + w];
        if (sel) sK[q][g] = v; else sQ[q][g] = v;
    }
    const __half* src = xTb + ((size_t)n * W_ + w) * H_ * C_;
    for (int i = t; i < H_ * (C_ / 4); i += 256) {
        int g = i / 64, s = (i % 64) * 4;
        *(h4*)&XTw[g][s] = *(const h4*)(src + (size_t)g * C_ + s);
    }
    __syncthreads();
    for (int i = t; i < H_ * H_; i += 256) {
        int hh = i / H_, g = i % H_;
        float s = 0.f;
        #pragma unroll
        for (int q = 0; q < QK_; ++q) s = fmaf(sQ[q][hh], sK[q][g], s);
        Ah[hh][g] = __float2half(s);
    }
    __syncthreads();
    if (t < H_) {
        float m = -1e30f;
        for (int g = 0; g < H_; ++g) m = fmaxf(m, __half2float(Ah[t][g]));
        float sum = 0.f;
        for (int g = 0; g < H_; ++g) {
            float e = __expf(__half2float(Ah[t][g]) - m);
            sum += e;
            Ah[t][g] = __float2half(e);
        }
        float inv = 1.f / sum;
        for (int g = 0; g < H_; ++g)
            Ah[t][g] = __float2half(__half2float(Ah[t][g]) * inv);
    }
    __syncthreads();
    int to = t >> 4, th = t & 15;
    for (int ot = 0; ot < 4; ++ot) {
        int ob = ot * 64 + to * 4;
        float acc[4][6];
        #pragma unroll
        for (int i = 0; i < 4; ++i)
            #pragma unroll
            for (int j = 0; j < 6; ++j) acc[i][j] = 0.f;
        for (int g = 0; g < H_; ++g) {
            float xr[4];
            h4_unpack(*(const h4*)&XTw[g][ob], xr);
            float ar[6];
            #pragma unroll
            for (int j = 0; j < 6; ++j) ar[j] = __half2float(Ah[th * 6 + j][g]);
            #pragma unroll
            for (int i = 0; i < 4; ++i)
                #pragma unroll
                for (int j = 0; j < 6; ++j) acc[i][j] = fmaf(xr[i], ar[j], acc[i][j]);
        }
        #pragma unroll
        for (int j = 0; j < 6; ++j) {
            int hh = th * 6 + j;
            __half* p = Tb + (((size_t)n * H_ + hh) * W_ + w) * C_ + ob;
            float old[4];
            h4_unpack(*(const h4*)p, old);
            *(h4*)p = h4_pack(old[0] + acc[0][j], old[1] + acc[1][j],
                              old[2] + acc[2][j], old[3] + acc[3][j]);
        }
    }
}

// K3: out_pre = Wv @ T per 64-px tile; writes OPb[n][c][px] fp16 + partial pools
template<int WSB>
__global__ __launch_bounds__(256) void ccca_wv1(
    const __half* __restrict__ Tb, const float* __restrict__ Wv,
    __half* __restrict__ OPb, float* __restrict__ psum, float* __restrict__ pmax)
{
    __shared__ __half Ts[64][C_ + 4];    // [px][c]
    __shared__ float sWv[C_][36];        // 32-col chunk of Wv
    int t = threadIdx.x;
    int n = blockIdx.x / 144, tile = blockIdx.x % 144;
    const __half* src = Tb + ((size_t)n * HW_ + tile * 64) * C_;
    for (int i = t; i < 64 * 64; i += 256) {
        int px = i / 64, s = (i % 64) * 4;
        *(h4*)&Ts[px][s] = *(const h4*)(src + (size_t)px * C_ + s);
    }
    int cb = t >> 4, pb = t & 15;
    float acc[16][4];
    #pragma unroll
    for (int j = 0; j < 16; ++j)
        #pragma unroll
        for (int p = 0; p < 4; ++p) acc[j][p] = 0.f;
    for (int ob = 0; ob < 8; ++ob) {
        __syncthreads();
        for (int i = t; i < C_ * 8; i += 256) {
            int r = i / 8, s = (i % 8) * 4;
            *(float4*)&sWv[r][s] = *(const float4*)(Wv + (size_t)r * C_ + ob * 32 + s);
        }
        __syncthreads();
        for (int oc = 0; oc < 32; oc += 4) {
            float tv[4][4];
            #pragma unroll
            for (int p = 0; p < 4; ++p)
                h4_unpack(*(const h4*)&Ts[pb * 4 + p][ob * 32 + oc], tv[p]);
            #pragma unroll
            for (int j = 0; j < 16; ++j) {
                float4 wv4 = *(const float4*)&sWv[cb * 16 + j][oc];
                #pragma unroll
                for (int p = 0; p < 4; ++p) {
                    acc[j][p] = fmaf(wv4.x, tv[p][0], acc[j][p]);
                    acc[j][p] = fmaf(wv4.y, tv[p][1], acc[j][p]);
                    acc[j][p] = fmaf(wv4.z, tv[p][2], acc[j][p]);
                    acc[j][p] = fmaf(wv4.w, tv[p][3], acc[j][p]);
                }
            }
        }
    }
    __half* dst = OPb + (size_t)n * C_ * HW_ + tile * 64;
    #pragma unroll
    for (int j = 0; j < 16; ++j) {
        int c = cb * 16 + j;
        *(h4*)(dst + (size_t)c * HW_ + pb * 4) =
            h4_pack(acc[j][0], acc[j][1], acc[j][2], acc[j][3]);
    }
    #pragma unroll
    for (int j = 0; j < 16; ++j) {
        float s = acc[j][0] + acc[j][1] + acc[j][2] + acc[j][3];
        float m = fmaxf(fmaxf(acc[j][0], acc[j][1]), fmaxf(acc[j][2], acc[j][3]));
        #pragma unroll
        for (int off = 1; off <= 8; off <<= 1) {
            s += __shfl_xor(s, off);
            m = fmaxf(m, __shfl_xor(m, off));
        }
        if (pb == 0) {
            size_t o = ((size_t)n * 144 + tile) * C_ + cb * 16 + j;
            psum[o] = s;
            pmax[o] = m;
        }
    }
}

// K4: reduce partials + SE MLP -> gate[n][c]
__global__ __launch_bounds__(256) void ccca_gate2(
    const float* __restrict__ psum, const float* __restrict__ pmax,
    const float* __restrict__ W1, const float* __restrict__ W2,
    float* __restrict__ gate)
{
    __shared__ float sa[C_], sm[C_], hs[C_];
    int n = blockIdx.x, t = threadIdx.x;
    float s = 0.f, m = -1e30f;
    for (int i = 0; i < 144; ++i) {
        s += psum[((size_t)n * 144 + i) * C_ + t];
        m = fmaxf(m, pmax[((size_t)n * 144 + i) * C_ + t]);
    }
    sa[t] = s * (1.f / 9216.f);
    sm[t] = m;
    __syncthreads();
    const float* w1r = W1 + (size_t)t * C_;
    float aa = 0.f, am = 0.f;
    for (int i = 0; i < C_; ++i) { float wv = w1r[i]; aa = fmaf(wv, sa[i], aa); am = fmaf(wv, sm[i], am); }
    hs[t] = fmaxf(aa, 0.f) + fmaxf(am, 0.f);
    __syncthreads();
    const float* w2r = W2 + (size_t)t * C_;
    float g = 0.f;
    for (int i = 0; i < C_; ++i) g = fmaf(w2r[i], hs[i], g);
    gate[n * C_ + t] = 1.f / (1.f + __expf(-g));
}

// K5: out = x + gama*gate*out_pre (elementwise)
template<int WSB>
__global__ __launch_bounds__(256) void ccca_final2(
    const float* __restrict__ x, const __half* __restrict__ OPb,
    const float* __restrict__ gate, const float* __restrict__ gama,
    float* __restrict__ out)
{
    float g0 = gama[0];
    const size_t total = (size_t)N_ * C_ * HW_ / 4;
    for (size_t i = (size_t)blockIdx.x * 256 + threadIdx.x; i < total; i += (size_t)gridDim.x * 256) {
        float4 xv = ((const float4*)x)[i];
        float ov[4];
        h4_unpack(((const h4*)OPb)[i], ov);
        size_t nc = (i * 4) / HW_;
        float sc = g0 * gate[nc];
        float4 r;
        r.x = fmaf(sc, ov[0], xv.x);
        r.y = fmaf(sc, ov[1], xv.y);
        r.z = fmaf(sc, ov[2], xv.z);
        r.w = fmaf(sc, ov[3], xv.w);
        ((float4*)out)[i] = r;
    }
}

// ===========================================================================
// FALLBACK PATH (round-1 kernels, proven correct)
// ===========================================================================

__global__ __launch_bounds__(256) void ccca_qk(
    const float* __restrict__ x, const float* __restrict__ Wq,
    const float* __restrict__ Wk, float* __restrict__ Qo, float* __restrict__ Ko)
{
    __shared__ float sWq[QK_ * C_];
    __shared__ float sWk[QK_ * C_];
    int t = threadIdx.x;
    for (int i = t; i < QK_ * C_; i += 256) { sWq[i] = Wq[i]; sWk[i] = Wk[i]; }
    __syncthreads();
    int n = blockIdx.x / 36;
    int p = (blockIdx.x % 36) * 256 + t;
    const float* xp = x + (size_t)n * C_ * HW_ + p;
    float qa[QK_] = {0.f, 0.f, 0.f, 0.f};
    float ka[QK_] = {0.f, 0.f, 0.f, 0.f};
    for (int c = 0; c < C_; ++c) {
        float v = xp[(size_t)c * HW_];
        #pragma unroll
        for (int q = 0; q < QK_; ++q) {
            qa[q] = fmaf(v, sWq[q * C_ + c], qa[q]);
            ka[q] = fmaf(v, sWk[q * C_ + c], ka[q]);
        }
    }
    size_t base = (size_t)n * QK_ * HW_ + p;
    #pragma unroll
    for (int q = 0; q < QK_; ++q) { Qo[base + q * HW_] = qa[q]; Ko[base + q * HW_] = ka[q]; }
}

__global__ __launch_bounds__(256) void ccca_row(
    const float* __restrict__ x, const float* __restrict__ Qw,
    const float* __restrict__ Kw, float* __restrict__ out)
{
    __shared__ float sQ[QK_][W_];
    __shared__ float sK[QK_][W_];
    __shared__ float A[W_][W_ + 1];
    __shared__ float Xs[64][W_ + 1];
    int t = threadIdx.x;
    int n = blockIdx.x / H_;
    int h = blockIdx.x % H_;
    for (int i = t; i < QK_ * W_; i += 256) {
        int q = i / W_, w = i % W_;
        size_t off = ((size_t)n * QK_ + q) * HW_ + h * W_ + w;
        sQ[q][w] = Qw[off];
        sK[q][w] = Kw[off];
    }
    __syncthreads();
    for (int i = t; i < W_ * W_; i += 256) {
        int w = i / W_, v = i % W_;
        float s = 0.f;
        #pragma unroll
        for (int q = 0; q < QK_; ++q) s = fmaf(sQ[q][w], sK[q][v], s);
        A[w][v] = s;
    }
    __syncthreads();
    if (t < W_) {
        float m = -1e30f;
        for (int v = 0; v < W_; ++v) m = fmaxf(m, A[t][v]);
        float sum = 0.f;
        for (int v = 0; v < W_; ++v) { float e = __expf(A[t][v] - m); A[t][v] = e; sum += e; }
        float inv = 1.f / sum;
        for (int v = 0; v < W_; ++v) A[t][v] *= inv;
    }
    __syncthreads();
    int to = t >> 4, tw = t & 15;
    for (int ot = 0; ot < 4; ++ot) {
        for (int i = t; i < 64 * W_ / 4; i += 256) {
            int f = i * 4;
            int o = f / W_, v = f % W_;
            float4 val = *(const float4*)(x + (((size_t)n * C_ + ot * 64 + o) * H_ + h) * W_ + v);
            Xs[o][v] = val.x; Xs[o][v + 1] = val.y; Xs[o][v + 2] = val.z; Xs[o][v + 3] = val.w;
        }
        __syncthreads();
        float acc[4][6];
        #pragma unroll
        for (int i = 0; i < 4; ++i)
            #pragma unroll
            for (int j = 0; j < 6; ++j) acc[i][j] = 0.f;
        for (int v = 0; v < W_; ++v) {
            float xr[4], ar[6];
            #pragma unroll
            for (int i = 0; i < 4; ++i) xr[i] = Xs[to * 4 + i][v];
            #pragma unroll
            for (int j = 0; j < 6; ++j) ar[j] = A[tw * 6 + j][v];
            #pragma unroll
            for (int i = 0; i < 4; ++i)
                #pragma unroll
                for (int j = 0; j < 6; ++j) acc[i][j] = fmaf(xr[i], ar[j], acc[i][j]);
        }
        #pragma unroll
        for (int i = 0; i < 4; ++i) {
            size_t ob = (((size_t)n * C_ + ot * 64 + to * 4 + i) * H_ + h) * W_ + tw * 6;
            #pragma unroll
            for (int j = 0; j < 6; ++j) out[ob + j] = acc[i][j];
        }
        __syncthreads();
    }
}

template<int WSB>
__global__ __launch_bounds__(256) void ccca_col(
    const float* __restrict__ x, const float* __restrict__ Qw,
    const float* __restrict__ Kw, float* __restrict__ out)
{
    __shared__ float sQ[QK_][H_];
    __shared__ float sK[QK_][H_];
    __shared__ float A[H_][H_ + 1];
    __shared__ float Xc[64][H_ + 1];
    int t = threadIdx.x;
    int n = blockIdx.x / W_;
    int w = blockIdx.x % W_;
    for (int i = t; i < QK_ * H_; i += 256) {
        int q = i / H_, hh = i % H_;
        size_t off = ((size_t)n * QK_ + q) * HW_ + hh * W_ + w;
        sQ[q][hh] = Qw[off];
        sK[q][hh] = Kw[off];
    }
    __syncthreads();
    for (int i = t; i < H_ * H_; i += 256) {
        int hh = i / H_, g = i % H_;
        float s = 0.f;
        #pragma unroll
        for (int q = 0; q < QK_; ++q) s = fmaf(sQ[q][hh], sK[q][g], s);
        A[hh][g] = s;
    }
    __syncthreads();
    if (t < H_) {
        float m = -1e30f;
        for (int g = 0; g < H_; ++g) m = fmaxf(m, A[t][g]);
        float sum = 0.f;
        for (int g = 0; g < H_; ++g) { float e = __expf(A[t][g] - m); A[t][g] = e; sum += e; }
        float inv = 1.f / sum;
        for (int g = 0; g < H_; ++g) A[t][g] *= inv;
    }
    __syncthreads();
    int to = t >> 4, th = t & 15;
    for (int ot = 0; ot < 4; ++ot) {
        for (int i = t; i < 64 * H_; i += 256) {
            int o = i / H_, g = i % H_;
            Xc[o][g] = x[(((size_t)n * C_ + ot * 64 + o) * H_ + g) * W_ + w];
        }
        __syncthreads();
        float acc[4][6];
        #pragma unroll
        for (int i = 0; i < 4; ++i)
            #pragma unroll
            for (int j = 0; j < 6; ++j) acc[i][j] = 0.f;
        for (int g = 0; g < H_; ++g) {
            float xr[4], ar[6];
            #pragma unroll
            for (int i = 0; i < 4; ++i) xr[i] = Xc[to * 4 + i][g];
            #pragma unroll
            for (int j = 0; j < 6; ++j) ar[j] = A[th * 6 + j][g];
            #pragma unroll
            for (int i = 0; i < 4; ++i)
                #pragma unroll
                for (int j = 0; j < 6; ++j) acc[i][j] = fmaf(xr[i], ar[j], acc[i][j]);
        }
        #pragma unroll
        for (int i = 0; i < 4; ++i)
            #pragma unroll
            for (int j = 0; j < 6; ++j) {
                size_t ob = (((size_t)n * C_ + ot * 64 + to * 4 + i) * H_ + th * 6 + j) * W_ + w;
                out[ob] += acc[i][j];
            }
        __syncthreads();
    }
}

__global__ __launch_bounds__(256) void ccca_wv(
    const float* __restrict__ Wv, float* __restrict__ out)
{
    __shared__ float Ts[C_][64];
    int t = threadIdx.x;
    int n = blockIdx.x / 144;
    int p0 = (blockIdx.x % 144) * 64;
    float* base = out + (size_t)n * C_ * HW_ + p0;
    for (int i = t; i < C_ * 16; i += 256) {
        int o = i >> 4, p4 = (i & 15) << 2;
        *(float4*)&Ts[o][p4] = *(const float4*)(base + (size_t)o * HW_ + p4);
    }
    __syncthreads();
    int cb = t >> 4, pb = t & 15;
    float acc[16][4];
    #pragma unroll
    for (int j = 0; j < 16; ++j)
        #pragma unroll
        for (int p = 0; p < 4; ++p) acc[j][p] = 0.f;
    for (int o = 0; o < C_; o += 4) {
        float tvv[4][4];
        #pragma unroll
        for (int k = 0; k < 4; ++k) {
            float4 q = *(float4*)&Ts[o + k][pb * 4];
            tvv[k][0] = q.x; tvv[k][1] = q.y; tvv[k][2] = q.z; tvv[k][3] = q.w;
        }
        #pragma unroll
        for (int j = 0; j < 16; ++j) {
            float4 wv = *(const float4*)(Wv + (size_t)(cb * 16 + j) * C_ + o);
            float wvv[4] = {wv.x, wv.y, wv.z, wv.w};
            #pragma unroll
            for (int k = 0; k < 4; ++k)
                #pragma unroll
                for (int p = 0; p < 4; ++p)
                    acc[j][p] = fmaf(wvv[k], tvv[k][p], acc[j][p]);
        }
    }
    #pragma unroll
    for (int j = 0; j < 16; ++j) {
        float4 r; r.x = acc[j][0]; r.y = acc[j][1]; r.z = acc[j][2]; r.w = acc[j][3];
        *(float4*)(base + (size_t)(cb * 16 + j) * HW_ + pb * 4) = r;
    }
}

__global__ __launch_bounds__(256) void ccca_pool(
    const float* __restrict__ out, float* __restrict__ avg, float* __restrict__ mx)
{
    int nc = blockIdx.x;
    const float* p = out + (size_t)nc * HW_;
    int t = threadIdx.x;
    float s = 0.f, m = -1e30f;
    for (int i = t; i < HW_; i += 256) { float v = p[i]; s += v; m = fmaxf(m, v); }
    #pragma unroll
    for (int off = 32; off > 0; off >>= 1) {
        s += __shfl_down(s, off);
        m = fmaxf(m, __shfl_down(m, off));
    }
    __shared__ float ss[4], smx[4];
    int wv = t >> 6;
    if ((t & 63) == 0) { ss[wv] = s; smx[wv] = m; }
    __syncthreads();
    if (t == 0) {
        s = ss[0] + ss[1] + ss[2] + ss[3];
        m = fmaxf(fmaxf(smx[0], smx[1]), fmaxf(smx[2], smx[3]));
        avg[nc] = s * (1.f / 9216.f);
        mx[nc] = m;
    }
}

__global__ __launch_bounds__(256) void ccca_gate(
    const float* __restrict__ avg, const float* __restrict__ mx,
    const float* __restrict__ W1, const float* __restrict__ W2,
    float* __restrict__ gate)
{
    __shared__ float sa[C_], sm[C_], hs[C_];
    int n = blockIdx.x, t = threadIdx.x;
    sa[t] = avg[n * C_ + t];
    sm[t] = mx[n * C_ + t];
    __syncthreads();
    const float* w1r = W1 + (size_t)t * C_;
    float aa = 0.f, am = 0.f;
    for (int i = 0; i < C_; ++i) { float wv = w1r[i]; aa = fmaf(wv, sa[i], aa); am = fmaf(wv, sm[i], am); }
    hs[t] = fmaxf(aa, 0.f) + fmaxf(am, 0.f);
    __syncthreads();
    const float* w2r = W2 + (size_t)t * C_;
    float g = 0.f;
    for (int i = 0; i < C_; ++i) g = fmaf(w2r[i], hs[i], g);
    gate[n * C_ + t] = 1.f / (1.f + __expf(-g));
}

__global__ __launch_bounds__(256) void ccca_final(
    const float* __restrict__ x, const float* __restrict__ gate,
    const float* __restrict__ gama, float* __restrict__ out)
{
    float g0 = gama[0];
    const size_t total = (size_t)N_ * C_ * HW_ / 4;
    for (size_t i = (size_t)blockIdx.x * 256 + threadIdx.x; i < total; i += (size_t)gridDim.x * 256) {
        float4 o = ((const float4*)out)[i];
        float4 xv = ((const float4*)x)[i];
        size_t nc = (i * 4) / HW_;
        float sc = g0 * gate[nc];
        o.x = fmaf(sc, o.x, xv.x);
        o.y = fmaf(sc, o.y, xv.y);
        o.z = fmaf(sc, o.z, xv.z);
        o.w = fmaf(sc, o.w, xv.w);
        ((float4*)out)[i] = o;
    }
}

// ===========================================================================

template<int WSB>
static void run_pipeline(bool fast,
                         const float* x, const float* Wq, const float* Wk, const float* Wv,
                         const float* W1, const float* W2, const float* gama,
                         float* out, char* ws, hipStream_t stream)
{
    if (fast) {
        const size_t TBE = (size_t)N_ * HW_ * C_;          // 37,748,736
        __half* xTb = (__half*)ws;                          // later reused as OPb
        __half* Tb  = (__half*)(ws + TBE * 2);
        float*  Qs  = (float*)(ws + TBE * 4);
        float*  Ks  = Qs + (size_t)N_ * QK_ * HW_;
        float*  gate = (float*)(ws + TBE * 4 + 4718592);
        // psum/pmax alias Qs/Ks (dead after ccca_col2)
        ccca_rowf<WSB><<<N_ * H_, 256, 0, stream>>>(x, Wq, Wk, Qs, Ks, xTb, Tb);
        ccca_col2<WSB><<<N_ * W_, 256, 0, stream>>>(Qs, Ks, xTb, Tb);
        ccca_wv1<WSB><<<N_ * 144, 256, 0, stream>>>(Tb, Wv, xTb, Qs, Ks);
        ccca_gate2<<<N_, 256, 0, stream>>>(Qs, Ks, W1, W2, gate);
        ccca_final2<WSB><<<2048, 256, 0, stream>>>(x, xTb, gate, gama, out);
    } else {
        float* wsf = (float*)ws;
        const size_t QSZ = (size_t)N_ * QK_ * HW_;
        float* Qb   = wsf;
        float* Kb   = wsf + QSZ;
        float* avg  = wsf + 2 * QSZ;
        float* mx   = avg + N_ * C_;
        float* gate = mx + N_ * C_;
        ccca_qk  <<<N_ * 36, 256, 0, stream>>>(x, Wq, Wk, Qb, Kb);
        ccca_row <<<N_ * H_, 256, 0, stream>>>(x, Qb, Kb, out);
        ccca_col<WSB><<<N_ * W_, 256, 0, stream>>>(x, Qb, Kb, out);
        ccca_wv  <<<N_ * 144, 256, 0, stream>>>(Wv, out);
        ccca_pool<<<N_ * C_, 256, 0, stream>>>(out, avg, mx);
        ccca_gate<<<N_, 256, 0, stream>>>(avg, mx, W1, W2, gate);
        ccca_final<<<2048, 256, 0, stream>>>(x, gate, gama, out);
    }
}

extern "C" void kernel_launch(void* const* d_in, const int* in_sizes, int n_in,
                              void* d_out, int out_size, void* d_ws, size_t ws_size,
                              hipStream_t stream)
{
    const float* x    = (const float*)d_in[0];
    const float* Wq   = (const float*)d_in[1];
    const float* Wk   = (const float*)d_in[2];
    const float* Wv   = (const float*)d_in[3];
    const float* W1   = (const float*)d_in[4];
    const float* W2   = (const float*)d_in[5];
    const float* gama = (const float*)d_in[6];
    float* out = (float*)d_out;
    char*  ws  = (char*)d_ws;

    const size_t WS_NEED = 155729920ull;   // 2*fp16 tensors + Q/K + gate
    bool fast = ws_size >= WS_NEED;
    int wsb = (int)(ws_size >> 24);        // 16MB buckets, reported via kernel name
    if (wsb > 15) wsb = 15;

    switch (wsb) {
        case 0:  run_pipeline<0>(fast, x, Wq, Wk, Wv, W1, W2, gama, out, ws, stream); break;
        case 1:  run_pipeline<1>(fast, x, Wq, Wk, Wv, W1, W2, gama, out, ws, stream); break;
        case 2:  run_pipeline<2>(fast, x, Wq, Wk, Wv, W1, W2, gama, out, ws, stream); break;
        case 3:  run_pipeline<3>(fast, x, Wq, Wk, Wv, W1, W2, gama, out, ws, stream); break;
        case 4:  run_pipeline<4>(fast, x, Wq, Wk, Wv, W1, W2, gama, out, ws, stream); break;
        case 5:  run_pipeline<5>(fast, x, Wq, Wk, Wv, W1, W2, gama, out, ws, stream); break;
        case 6:  run_pipeline<6>(fast, x, Wq, Wk, Wv, W1, W2, gama, out, ws, stream); break;
        case 7:  run_pipeline<7>(fast, x, Wq, Wk, Wv, W1, W2, gama, out, ws, stream); break;
        case 8:  run_pipeline<8>(fast, x, Wq, Wk, Wv, W1, W2, gama, out, ws, stream); break;
        case 9:  run_pipeline<9>(fast, x, Wq, Wk, Wv, W1, W2, gama, out, ws, stream); break;
        case 10: run_pipeline<10>(fast, x, Wq, Wk, Wv, W1, W2, gama, out, ws, stream); break;
        case 11: run_pipeline<11>(fast, x, Wq, Wk, Wv, W1, W2, gama, out, ws, stream); break;
        case 12: run_pipeline<12>(fast, x, Wq, Wk, Wv, W1, W2, gama, out, ws, stream); break;
        case 13: run_pipeline<13>(fast, x, Wq, Wk, Wv, W1, W2, gama, out, ws, stream); break;
        case 14: run_pipeline<14>(fast, x, Wq, Wk, Wv, W1, W2, gama, out, ws, stream); break;
        default: run_pipeline<15>(fast, x, Wq, Wk, Wv, W1, W2, gama, out, ws, stream); break;
    }
}

// Round 3
// 760.586 us; speedup vs baseline: 2.8079x; 1.2944x over previous
//
#include <hip/hip_runtime.h>
#include <hip/hip_fp16.h>

#define N_  16
#define C_  256
#define H_  96
#define W_  96
#define HW_ 9216
#define QK_ 4

struct alignas(8) h4 { __half2 a, b; };

__device__ inline void h4_unpack(h4 v, float* f) {
    float2 lo = __half22float2(v.a), hi = __half22float2(v.b);
    f[0] = lo.x; f[1] = lo.y; f[2] = hi.x; f[3] = hi.y;
}
__device__ inline h4 h4_pack(float a, float b, float c, float d) {
    h4 r; r.a = __floats2half2_rn(a, b); r.b = __floats2half2_rn(c, d); return r;
}

typedef __attribute__((ext_vector_type(8))) _Float16 f16x8;
typedef __attribute__((ext_vector_type(4))) float    f32x4;

// ===========================================================================
// FAST PATH
// ===========================================================================

// K1: per (n,h): stage x row -> Q,K -> row softmax -> T1 -> Tb[n][px][c] fp16
//     Also emits xTb[n][w][h][c] (transposed copy for col kernel).
__global__ __launch_bounds__(256) void ccca_rowf(
    const float* __restrict__ x, const float* __restrict__ Wq, const float* __restrict__ Wk,
    float* __restrict__ Qs, float* __restrict__ Ks,
    __half* __restrict__ xTb, __half* __restrict__ Tb)
{
    __shared__ __half XsT[W_][C_ + 4];   // [w][c]
    __shared__ __half Ah[W_][100];
    __shared__ float sQ[QK_][W_];
    __shared__ float sK[QK_][W_];
    int t = threadIdx.x;
    int n = blockIdx.x / H_, h = blockIdx.x % H_;
    const float* xb = x + (size_t)n * C_ * HW_ + (size_t)h * W_;
    for (int i = t; i < C_ * (W_ / 4); i += 256) {
        int c = i / 24, s4 = (i % 24) * 4;
        float4 v = *(const float4*)(xb + (size_t)c * HW_ + s4);
        XsT[s4    ][c] = __float2half(v.x);
        XsT[s4 + 1][c] = __float2half(v.y);
        XsT[s4 + 2][c] = __float2half(v.z);
        XsT[s4 + 3][c] = __float2half(v.w);
    }
    __syncthreads();
    {
        __half* xd = xTb + ((size_t)n * W_ * H_ + h) * C_;
        for (int i = t; i < W_ * (C_ / 4); i += 256) {
            int w = i / 64, s = (i % 64) * 4;
            *(h4*)(xd + (size_t)w * H_ * C_ + s) = *(const h4*)&XsT[w][s];
        }
    }
    for (int i = t; i < 2 * QK_ * W_; i += 256) {
        int sel = i / (QK_ * W_), r = i % (QK_ * W_);
        int q = r / W_, w = r % W_;
        const float* wr = (sel ? Wk : Wq) + q * C_;
        float s = 0.f;
        for (int c = 0; c < C_; ++c) s = fmaf(wr[c], __half2float(XsT[w][c]), s);
        if (sel) { sK[q][w] = s; Ks[(((size_t)n * QK_ + q) * H_ + h) * W_ + w] = s; }
        else     { sQ[q][w] = s; Qs[(((size_t)n * QK_ + q) * H_ + h) * W_ + w] = s; }
    }
    __syncthreads();
    for (int i = t; i < W_ * W_; i += 256) {
        int w = i / W_, v = i % W_;
        float s = 0.f;
        #pragma unroll
        for (int q = 0; q < QK_; ++q) s = fmaf(sQ[q][w], sK[q][v], s);
        Ah[w][v] = __float2half(s);
    }
    __syncthreads();
    if (t < W_) {
        float m = -1e30f;
        for (int v = 0; v < W_; ++v) m = fmaxf(m, __half2float(Ah[t][v]));
        float sum = 0.f;
        for (int v = 0; v < W_; ++v) {
            float e = __expf(__half2float(Ah[t][v]) - m);
            sum += e;
            Ah[t][v] = __float2half(e);
        }
        float inv = 1.f / sum;
        for (int v = 0; v < W_; ++v)
            Ah[t][v] = __float2half(__half2float(Ah[t][v]) * inv);
    }
    __syncthreads();
    int to = t >> 4, tw = t & 15;
    __half* Tn = Tb + ((size_t)n * H_ + h) * W_ * C_;
    for (int ot = 0; ot < 4; ++ot) {
        int ob = ot * 64 + to * 4;
        float acc[4][6];
        #pragma unroll
        for (int i = 0; i < 4; ++i)
            #pragma unroll
            for (int j = 0; j < 6; ++j) acc[i][j] = 0.f;
        for (int v = 0; v < W_; ++v) {
            float xr[4];
            h4_unpack(*(const h4*)&XsT[v][ob], xr);
            float ar[6];
            #pragma unroll
            for (int j = 0; j < 6; ++j) ar[j] = __half2float(Ah[tw * 6 + j][v]);
            #pragma unroll
            for (int i = 0; i < 4; ++i)
                #pragma unroll
                for (int j = 0; j < 6; ++j) acc[i][j] = fmaf(xr[i], ar[j], acc[i][j]);
        }
        #pragma unroll
        for (int j = 0; j < 6; ++j) {
            int w = tw * 6 + j;
            *(h4*)(Tn + (size_t)w * C_ + ob) =
                h4_pack(acc[0][j], acc[1][j], acc[2][j], acc[3][j]);
        }
    }
}

// K2: per (n,w): col attention; values from xTb (coalesced); RMW into Tb.
__global__ __launch_bounds__(256) void ccca_col2(
    const float* __restrict__ Qs, const float* __restrict__ Ks,
    const __half* __restrict__ xTb, __half* __restrict__ Tb)
{
    __shared__ __half XTw[H_][C_ + 4];   // [g][c]
    __shared__ __half Ah[H_][100];
    __shared__ float sQ[QK_][H_];
    __shared__ float sK[QK_][H_];
    int t = threadIdx.x;
    int n = blockIdx.x / W_, w = blockIdx.x % W_;
    for (int i = t; i < 2 * QK_ * H_; i += 256) {
        int sel = i / (QK_ * H_), r = i % (QK_ * H_);
        int q = r / H_, g = r % H_;
        float v = (sel ? Ks : Qs)[(((size_t)n * QK_ + q) * H_ + g) * W_ + w];
        if (sel) sK[q][g] = v; else sQ[q][g] = v;
    }
    const __half* src = xTb + ((size_t)n * W_ + w) * H_ * C_;
    for (int i = t; i < H_ * (C_ / 4); i += 256) {
        int g = i / 64, s = (i % 64) * 4;
        *(h4*)&XTw[g][s] = *(const h4*)(src + (size_t)g * C_ + s);
    }
    __syncthreads();
    for (int i = t; i < H_ * H_; i += 256) {
        int hh = i / H_, g = i % H_;
        float s = 0.f;
        #pragma unroll
        for (int q = 0; q < QK_; ++q) s = fmaf(sQ[q][hh], sK[q][g], s);
        Ah[hh][g] = __float2half(s);
    }
    __syncthreads();
    if (t < H_) {
        float m = -1e30f;
        for (int g = 0; g < H_; ++g) m = fmaxf(m, __half2float(Ah[t][g]));
        float sum = 0.f;
        for (int g = 0; g < H_; ++g) {
            float e = __expf(__half2float(Ah[t][g]) - m);
            sum += e;
            Ah[t][g] = __float2half(e);
        }
        float inv = 1.f / sum;
        for (int g = 0; g < H_; ++g)
            Ah[t][g] = __float2half(__half2float(Ah[t][g]) * inv);
    }
    __syncthreads();
    int to = t >> 4, th = t & 15;
    for (int ot = 0; ot < 4; ++ot) {
        int ob = ot * 64 + to * 4;
        float acc[4][6];
        #pragma unroll
        for (int i = 0; i < 4; ++i)
            #pragma unroll
            for (int j = 0; j < 6; ++j) acc[i][j] = 0.f;
        for (int g = 0; g < H_; ++g) {
            float xr[4];
            h4_unpack(*(const h4*)&XTw[g][ob], xr);
            float ar[6];
            #pragma unroll
            for (int j = 0; j < 6; ++j) ar[j] = __half2float(Ah[th * 6 + j][g]);
            #pragma unroll
            for (int i = 0; i < 4; ++i)
                #pragma unroll
                for (int j = 0; j < 6; ++j) acc[i][j] = fmaf(xr[i], ar[j], acc[i][j]);
        }
        #pragma unroll
        for (int j = 0; j < 6; ++j) {
            int hh = th * 6 + j;
            __half* p = Tb + (((size_t)n * H_ + hh) * W_ + w) * C_ + ob;
            float old[4];
            h4_unpack(*(const h4*)p, old);
            *(h4*)p = h4_pack(old[0] + acc[0][j], old[1] + acc[1][j],
                              old[2] + acc[2][j], old[3] + acc[3][j]);
        }
    }
}

// K2.5: convert Wv fp32 -> fp16 (row-major [256][256])
__global__ __launch_bounds__(256) void ccca_cvtwv(
    const float* __restrict__ Wv, __half* __restrict__ Wvh)
{
    int gid = blockIdx.x * 256 + threadIdx.x;           // 64 blocks x 256
    float4 v = ((const float4*)Wv)[gid];
    ((h4*)Wvh)[gid] = h4_pack(v.x, v.y, v.z, v.w);
}

// K3 (MFMA): OPb[n][c][px] = sum_o Wvh[c][o] * Tb[n][px][o]; fused partial pools.
// Block = (n, 64-px tile), 4 waves; wave wd owns c in [64wd, 64wd+64).
__global__ __launch_bounds__(256) void ccca_wvm(
    const __half* __restrict__ Tb, const __half* __restrict__ Wvh,
    __half* __restrict__ OPb, float* __restrict__ psum, float* __restrict__ pmax)
{
    int t = threadIdx.x;
    int wd = t >> 6, lane = t & 63;
    int ln15 = lane & 15, kg = lane >> 4;
    int n = blockIdx.x / 144, tile = blockIdx.x % 144;

    const _Float16* Ab = (const _Float16*)Wvh + (size_t)(64 * wd + ln15) * C_ + kg * 8;
    const _Float16* Bb = (const _Float16*)Tb +
                         ((size_t)n * HW_ + tile * 64 + ln15) * C_ + kg * 8;

    f32x4 acc[4][4];
    #pragma unroll
    for (int i = 0; i < 4; ++i)
        #pragma unroll
        for (int p = 0; p < 4; ++p) acc[i][p] = (f32x4){0.f, 0.f, 0.f, 0.f};

    #pragma unroll
    for (int kk = 0; kk < 8; ++kk) {
        f16x8 a[4], b[4];
        #pragma unroll
        for (int i = 0; i < 4; ++i)
            a[i] = *(const f16x8*)(Ab + (size_t)i * 16 * C_ + kk * 32);
        #pragma unroll
        for (int p = 0; p < 4; ++p)
            b[p] = *(const f16x8*)(Bb + (size_t)p * 16 * C_ + kk * 32);
        #pragma unroll
        for (int i = 0; i < 4; ++i)
            #pragma unroll
            for (int p = 0; p < 4; ++p)
                acc[i][p] = __builtin_amdgcn_mfma_f32_16x16x32_f16(a[i], b[p], acc[i][p], 0, 0, 0);
    }

    // store OPb: c = 64wd+16i+4kg+r, px = tile*64+16p+ln15
    __half* dst = OPb + (size_t)n * C_ * HW_;
    #pragma unroll
    for (int i = 0; i < 4; ++i) {
        #pragma unroll
        for (int r = 0; r < 4; ++r) {
            int c = 64 * wd + 16 * i + 4 * kg + r;
            #pragma unroll
            for (int p = 0; p < 4; ++p) {
                int px = tile * 64 + 16 * p + ln15;
                dst[(size_t)c * HW_ + px] = __float2half(acc[i][p][r]);
            }
        }
    }

    // fused pooling: per c, sum/max over the tile's 64 px
    #pragma unroll
    for (int i = 0; i < 4; ++i) {
        float ps[4] = {0.f, 0.f, 0.f, 0.f};
        float pm[4] = {-1e30f, -1e30f, -1e30f, -1e30f};
        #pragma unroll
        for (int p = 0; p < 4; ++p)
            #pragma unroll
            for (int r = 0; r < 4; ++r) {
                ps[r] += acc[i][p][r];
                pm[r] = fmaxf(pm[r], acc[i][p][r]);
            }
        #pragma unroll
        for (int m = 1; m <= 8; m <<= 1)
            #pragma unroll
            for (int r = 0; r < 4; ++r) {
                ps[r] += __shfl_xor(ps[r], m);
                pm[r] = fmaxf(pm[r], __shfl_xor(pm[r], m));
            }
        if (ln15 == 0) {
            size_t base = ((size_t)n * 144 + tile) * C_ + 64 * wd + 16 * i + 4 * kg;
            #pragma unroll
            for (int r = 0; r < 4; ++r) { psum[base + r] = ps[r]; pmax[base + r] = pm[r]; }
        }
    }
}

// K3-fallback (VALU version, used only if ws too small for Wvh)
__global__ __launch_bounds__(256) void ccca_wv1(
    const __half* __restrict__ Tb, const float* __restrict__ Wv,
    __half* __restrict__ OPb, float* __restrict__ psum, float* __restrict__ pmax)
{
    __shared__ __half Ts[64][C_ + 4];
    __shared__ float sWv[C_][36];
    int t = threadIdx.x;
    int n = blockIdx.x / 144, tile = blockIdx.x % 144;
    const __half* src = Tb + ((size_t)n * HW_ + tile * 64) * C_;
    for (int i = t; i < 64 * 64; i += 256) {
        int px = i / 64, s = (i % 64) * 4;
        *(h4*)&Ts[px][s] = *(const h4*)(src + (size_t)px * C_ + s);
    }
    int cb = t >> 4, pb = t & 15;
    float acc[16][4];
    #pragma unroll
    for (int j = 0; j < 16; ++j)
        #pragma unroll
        for (int p = 0; p < 4; ++p) acc[j][p] = 0.f;
    for (int ob = 0; ob < 8; ++ob) {
        __syncthreads();
        for (int i = t; i < C_ * 8; i += 256) {
            int r = i / 8, s = (i % 8) * 4;
            *(float4*)&sWv[r][s] = *(const float4*)(Wv + (size_t)r * C_ + ob * 32 + s);
        }
        __syncthreads();
        for (int oc = 0; oc < 32; oc += 4) {
            float tv[4][4];
            #pragma unroll
            for (int p = 0; p < 4; ++p)
                h4_unpack(*(const h4*)&Ts[pb * 4 + p][ob * 32 + oc], tv[p]);
            #pragma unroll
            for (int j = 0; j < 16; ++j) {
                float4 wv4 = *(const float4*)&sWv[cb * 16 + j][oc];
                #pragma unroll
                for (int p = 0; p < 4; ++p) {
                    acc[j][p] = fmaf(wv4.x, tv[p][0], acc[j][p]);
                    acc[j][p] = fmaf(wv4.y, tv[p][1], acc[j][p]);
                    acc[j][p] = fmaf(wv4.z, tv[p][2], acc[j][p]);
                    acc[j][p] = fmaf(wv4.w, tv[p][3], acc[j][p]);
                }
            }
        }
    }
    __half* dst = OPb + (size_t)n * C_ * HW_ + tile * 64;
    #pragma unroll
    for (int j = 0; j < 16; ++j) {
        int c = cb * 16 + j;
        *(h4*)(dst + (size_t)c * HW_ + pb * 4) =
            h4_pack(acc[j][0], acc[j][1], acc[j][2], acc[j][3]);
    }
    #pragma unroll
    for (int j = 0; j < 16; ++j) {
        float s = acc[j][0] + acc[j][1] + acc[j][2] + acc[j][3];
        float m = fmaxf(fmaxf(acc[j][0], acc[j][1]), fmaxf(acc[j][2], acc[j][3]));
        #pragma unroll
        for (int off = 1; off <= 8; off <<= 1) {
            s += __shfl_xor(s, off);
            m = fmaxf(m, __shfl_xor(m, off));
        }
        if (pb == 0) {
            size_t o = ((size_t)n * 144 + tile) * C_ + cb * 16 + j;
            psum[o] = s;
            pmax[o] = m;
        }
    }
}

// K4: reduce partials + SE MLP -> gate[n][c]
__global__ __launch_bounds__(256) void ccca_gate2(
    const float* __restrict__ psum, const float* __restrict__ pmax,
    const float* __restrict__ W1, const float* __restrict__ W2,
    float* __restrict__ gate)
{
    __shared__ float sa[C_], sm[C_], hs[C_];
    int n = blockIdx.x, t = threadIdx.x;
    float s = 0.f, m = -1e30f;
    for (int i = 0; i < 144; ++i) {
        s += psum[((size_t)n * 144 + i) * C_ + t];
        m = fmaxf(m, pmax[((size_t)n * 144 + i) * C_ + t]);
    }
    sa[t] = s * (1.f / 9216.f);
    sm[t] = m;
    __syncthreads();
    const float* w1r = W1 + (size_t)t * C_;
    float aa = 0.f, am = 0.f;
    for (int i = 0; i < C_; ++i) { float wv = w1r[i]; aa = fmaf(wv, sa[i], aa); am = fmaf(wv, sm[i], am); }
    hs[t] = fmaxf(aa, 0.f) + fmaxf(am, 0.f);
    __syncthreads();
    const float* w2r = W2 + (size_t)t * C_;
    float g = 0.f;
    for (int i = 0; i < C_; ++i) g = fmaf(w2r[i], hs[i], g);
    gate[n * C_ + t] = 1.f / (1.f + __expf(-g));
}

// K5: out = x + gama*gate*out_pre (elementwise)
__global__ __launch_bounds__(256) void ccca_final2(
    const float* __restrict__ x, const __half* __restrict__ OPb,
    const float* __restrict__ gate, const float* __restrict__ gama,
    float* __restrict__ out)
{
    float g0 = gama[0];
    const size_t total = (size_t)N_ * C_ * HW_ / 4;
    for (size_t i = (size_t)blockIdx.x * 256 + threadIdx.x; i < total; i += (size_t)gridDim.x * 256) {
        float4 xv = ((const float4*)x)[i];
        float ov[4];
        h4_unpack(((const h4*)OPb)[i], ov);
        size_t nc = (i * 4) / HW_;
        float sc = g0 * gate[nc];
        float4 r;
        r.x = fmaf(sc, ov[0], xv.x);
        r.y = fmaf(sc, ov[1], xv.y);
        r.z = fmaf(sc, ov[2], xv.z);
        r.w = fmaf(sc, ov[3], xv.w);
        ((float4*)out)[i] = r;
    }
}

// ===========================================================================
// FALLBACK PATH (round-1 kernels, proven correct)
// ===========================================================================

__global__ __launch_bounds__(256) void ccca_qk(
    const float* __restrict__ x, const float* __restrict__ Wq,
    const float* __restrict__ Wk, float* __restrict__ Qo, float* __restrict__ Ko)
{
    __shared__ float sWq[QK_ * C_];
    __shared__ float sWk[QK_ * C_];
    int t = threadIdx.x;
    for (int i = t; i < QK_ * C_; i += 256) { sWq[i] = Wq[i]; sWk[i] = Wk[i]; }
    __syncthreads();
    int n = blockIdx.x / 36;
    int p = (blockIdx.x % 36) * 256 + t;
    const float* xp = x + (size_t)n * C_ * HW_ + p;
    float qa[QK_] = {0.f, 0.f, 0.f, 0.f};
    float ka[QK_] = {0.f, 0.f, 0.f, 0.f};
    for (int c = 0; c < C_; ++c) {
        float v = xp[(size_t)c * HW_];
        #pragma unroll
        for (int q = 0; q < QK_; ++q) {
            qa[q] = fmaf(v, sWq[q * C_ + c], qa[q]);
            ka[q] = fmaf(v, sWk[q * C_ + c], ka[q]);
        }
    }
    size_t base = (size_t)n * QK_ * HW_ + p;
    #pragma unroll
    for (int q = 0; q < QK_; ++q) { Qo[base + q * HW_] = qa[q]; Ko[base + q * HW_] = ka[q]; }
}

__global__ __launch_bounds__(256) void ccca_row(
    const float* __restrict__ x, const float* __restrict__ Qw,
    const float* __restrict__ Kw, float* __restrict__ out)
{
    __shared__ float sQ[QK_][W_];
    __shared__ float sK[QK_][W_];
    __shared__ float A[W_][W_ + 1];
    __shared__ float Xs[64][W_ + 1];
    int t = threadIdx.x;
    int n = blockIdx.x / H_;
    int h = blockIdx.x % H_;
    for (int i = t; i < QK_ * W_; i += 256) {
        int q = i / W_, w = i % W_;
        size_t off = ((size_t)n * QK_ + q) * HW_ + h * W_ + w;
        sQ[q][w] = Qw[off];
        sK[q][w] = Kw[off];
    }
    __syncthreads();
    for (int i = t; i < W_ * W_; i += 256) {
        int w = i / W_, v = i % W_;
        float s = 0.f;
        #pragma unroll
        for (int q = 0; q < QK_; ++q) s = fmaf(sQ[q][w], sK[q][v], s);
        A[w][v] = s;
    }
    __syncthreads();
    if (t < W_) {
        float m = -1e30f;
        for (int v = 0; v < W_; ++v) m = fmaxf(m, A[t][v]);
        float sum = 0.f;
        for (int v = 0; v < W_; ++v) { float e = __expf(A[t][v] - m); A[t][v] = e; sum += e; }
        float inv = 1.f / sum;
        for (int v = 0; v < W_; ++v) A[t][v] *= inv;
    }
    __syncthreads();
    int to = t >> 4, tw = t & 15;
    for (int ot = 0; ot < 4; ++ot) {
        for (int i = t; i < 64 * W_ / 4; i += 256) {
            int f = i * 4;
            int o = f / W_, v = f % W_;
            float4 val = *(const float4*)(x + (((size_t)n * C_ + ot * 64 + o) * H_ + h) * W_ + v);
            Xs[o][v] = val.x; Xs[o][v + 1] = val.y; Xs[o][v + 2] = val.z; Xs[o][v + 3] = val.w;
        }
        __syncthreads();
        float acc[4][6];
        #pragma unroll
        for (int i = 0; i < 4; ++i)
            #pragma unroll
            for (int j = 0; j < 6; ++j) acc[i][j] = 0.f;
        for (int v = 0; v < W_; ++v) {
            float xr[4], ar[6];
            #pragma unroll
            for (int i = 0; i < 4; ++i) xr[i] = Xs[to * 4 + i][v];
            #pragma unroll
            for (int j = 0; j < 6; ++j) ar[j] = A[tw * 6 + j][v];
            #pragma unroll
            for (int i = 0; i < 4; ++i)
                #pragma unroll
                for (int j = 0; j < 6; ++j) acc[i][j] = fmaf(xr[i], ar[j], acc[i][j]);
        }
        #pragma unroll
        for (int i = 0; i < 4; ++i) {
            size_t ob = (((size_t)n * C_ + ot * 64 + to * 4 + i) * H_ + h) * W_ + tw * 6;
            #pragma unroll
            for (int j = 0; j < 6; ++j) out[ob + j] = acc[i][j];
        }
        __syncthreads();
    }
}

__global__ __launch_bounds__(256) void ccca_col(
    const float* __restrict__ x, const float* __restrict__ Qw,
    const float* __restrict__ Kw, float* __restrict__ out)
{
    __shared__ float sQ[QK_][H_];
    __shared__ float sK[QK_][H_];
    __shared__ float A[H_][H_ + 1];
    __shared__ float Xc[64][H_ + 1];
    int t = threadIdx.x;
    int n = blockIdx.x / W_;
    int w = blockIdx.x % W_;
    for (int i = t; i < QK_ * H_; i += 256) {
        int q = i / H_, hh = i % H_;
        size_t off = ((size_t)n * QK_ + q) * HW_ + hh * W_ + w;
        sQ[q][hh] = Qw[off];
        sK[q][hh] = Kw[off];
    }
    __syncthreads();
    for (int i = t; i < H_ * H_; i += 256) {
        int hh = i / H_, g = i % H_;
        float s = 0.f;
        #pragma unroll
        for (int q = 0; q < QK_; ++q) s = fmaf(sQ[q][hh], sK[q][g], s);
        A[hh][g] = s;
    }
    __syncthreads();
    if (t < H_) {
        float m = -1e30f;
        for (int g = 0; g < H_; ++g) m = fmaxf(m, A[t][g]);
        float sum = 0.f;
        for (int g = 0; g < H_; ++g) { float e = __expf(A[t][g] - m); A[t][g] = e; sum += e; }
        float inv = 1.f / sum;
        for (int g = 0; g < H_; ++g) A[t][g] *= inv;
    }
    __syncthreads();
    int to = t >> 4, th = t & 15;
    for (int ot = 0; ot < 4; ++ot) {
        for (int i = t; i < 64 * H_; i += 256) {
            int o = i / H_, g = i % H_;
            Xc[o][g] = x[(((size_t)n * C_ + ot * 64 + o) * H_ + g) * W_ + w];
        }
        __syncthreads();
        float acc[4][6];
        #pragma unroll
        for (int i = 0; i < 4; ++i)
            #pragma unroll
            for (int j = 0; j < 6; ++j) acc[i][j] = 0.f;
        for (int g = 0; g < H_; ++g) {
            float xr[4], ar[6];
            #pragma unroll
            for (int i = 0; i < 4; ++i) xr[i] = Xc[to * 4 + i][g];
            #pragma unroll
            for (int j = 0; j < 6; ++j) ar[j] = A[th * 6 + j][g];
            #pragma unroll
            for (int i = 0; i < 4; ++i)
                #pragma unroll
                for (int j = 0; j < 6; ++j) acc[i][j] = fmaf(xr[i], ar[j], acc[i][j]);
        }
        #pragma unroll
        for (int i = 0; i < 4; ++i)
            #pragma unroll
            for (int j = 0; j < 6; ++j) {
                size_t ob = (((size_t)n * C_ + ot * 64 + to * 4 + i) * H_ + th * 6 + j) * W_ + w;
                out[ob] += acc[i][j];
            }
        __syncthreads();
    }
}

__global__ __launch_bounds__(256) void ccca_wv(
    const float* __restrict__ Wv, float* __restrict__ out)
{
    __shared__ float Ts[C_][64];
    int t = threadIdx.x;
    int n = blockIdx.x / 144;
    int p0 = (blockIdx.x % 144) * 64;
    float* base = out + (size_t)n * C_ * HW_ + p0;
    for (int i = t; i < C_ * 16; i += 256) {
        int o = i >> 4, p4 = (i & 15) << 2;
        *(float4*)&Ts[o][p4] = *(const float4*)(base + (size_t)o * HW_ + p4);
    }
    __syncthreads();
    int cb = t >> 4, pb = t & 15;
    float acc[16][4];
    #pragma unroll
    for (int j = 0; j < 16; ++j)
        #pragma unroll
        for (int p = 0; p < 4; ++p) acc[j][p] = 0.f;
    for (int o = 0; o < C_; o += 4) {
        float tvv[4][4];
        #pragma unroll
        for (int k = 0; k < 4; ++k) {
            float4 q = *(float4*)&Ts[o + k][pb * 4];
            tvv[k][0] = q.x; tvv[k][1] = q.y; tvv[k][2] = q.z; tvv[k][3] = q.w;
        }
        #pragma unroll
        for (int j = 0; j < 16; ++j) {
            float4 wv = *(const float4*)(Wv + (size_t)(cb * 16 + j) * C_ + o);
            float wvv[4] = {wv.x, wv.y, wv.z, wv.w};
            #pragma unroll
            for (int k = 0; k < 4; ++k)
                #pragma unroll
                for (int p = 0; p < 4; ++p)
                    acc[j][p] = fmaf(wvv[k], tvv[k][p], acc[j][p]);
        }
    }
    #pragma unroll
    for (int j = 0; j < 16; ++j) {
        float4 r; r.x = acc[j][0]; r.y = acc[j][1]; r.z = acc[j][2]; r.w = acc[j][3];
        *(float4*)(base + (size_t)(cb * 16 + j) * HW_ + pb * 4) = r;
    }
}

__global__ __launch_bounds__(256) void ccca_pool(
    const float* __restrict__ out, float* __restrict__ avg, float* __restrict__ mx)
{
    int nc = blockIdx.x;
    const float* p = out + (size_t)nc * HW_;
    int t = threadIdx.x;
    float s = 0.f, m = -1e30f;
    for (int i = t; i < HW_; i += 256) { float v = p[i]; s += v; m = fmaxf(m, v); }
    #pragma unroll
    for (int off = 32; off > 0; off >>= 1) {
        s += __shfl_down(s, off);
        m = fmaxf(m, __shfl_down(m, off));
    }
    __shared__ float ss[4], smx[4];
    int wv = t >> 6;
    if ((t & 63) == 0) { ss[wv] = s; smx[wv] = m; }
    __syncthreads();
    if (t == 0) {
        s = ss[0] + ss[1] + ss[2] + ss[3];
        m = fmaxf(fmaxf(smx[0], smx[1]), fmaxf(smx[2], smx[3]));
        avg[nc] = s * (1.f / 9216.f);
        mx[nc] = m;
    }
}

__global__ __launch_bounds__(256) void ccca_gate(
    const float* __restrict__ avg, const float* __restrict__ mx,
    const float* __restrict__ W1, const float* __restrict__ W2,
    float* __restrict__ gate)
{
    __shared__ float sa[C_], sm[C_], hs[C_];
    int n = blockIdx.x, t = threadIdx.x;
    sa[t] = avg[n * C_ + t];
    sm[t] = mx[n * C_ + t];
    __syncthreads();
    const float* w1r = W1 + (size_t)t * C_;
    float aa = 0.f, am = 0.f;
    for (int i = 0; i < C_; ++i) { float wv = w1r[i]; aa = fmaf(wv, sa[i], aa); am = fmaf(wv, sm[i], am); }
    hs[t] = fmaxf(aa, 0.f) + fmaxf(am, 0.f);
    __syncthreads();
    const float* w2r = W2 + (size_t)t * C_;
    float g = 0.f;
    for (int i = 0; i < C_; ++i) g = fmaf(w2r[i], hs[i], g);
    gate[n * C_ + t] = 1.f / (1.f + __expf(-g));
}

__global__ __launch_bounds__(256) void ccca_final(
    const float* __restrict__ x, const float* __restrict__ gate,
    const float* __restrict__ gama, float* __restrict__ out)
{
    float g0 = gama[0];
    const size_t total = (size_t)N_ * C_ * HW_ / 4;
    for (size_t i = (size_t)blockIdx.x * 256 + threadIdx.x; i < total; i += (size_t)gridDim.x * 256) {
        float4 o = ((const float4*)out)[i];
        float4 xv = ((const float4*)x)[i];
        size_t nc = (i * 4) / HW_;
        float sc = g0 * gate[nc];
        o.x = fmaf(sc, o.x, xv.x);
        o.y = fmaf(sc, o.y, xv.y);
        o.z = fmaf(sc, o.z, xv.z);
        o.w = fmaf(sc, o.w, xv.w);
        ((float4*)out)[i] = o;
    }
}

// ===========================================================================

extern "C" void kernel_launch(void* const* d_in, const int* in_sizes, int n_in,
                              void* d_out, int out_size, void* d_ws, size_t ws_size,
                              hipStream_t stream)
{
    const float* x    = (const float*)d_in[0];
    const float* Wq   = (const float*)d_in[1];
    const float* Wk   = (const float*)d_in[2];
    const float* Wv   = (const float*)d_in[3];
    const float* W1   = (const float*)d_in[4];
    const float* W2   = (const float*)d_in[5];
    const float* gama = (const float*)d_in[6];
    float* out = (float*)d_out;
    char*  ws  = (char*)d_ws;

    const size_t TBE      = (size_t)N_ * HW_ * C_;          // 37,748,736 elems
    const size_t WS_NEED  = 155729920ull;                   // fast path, VALU wv
    const size_t WS_NEED2 = WS_NEED + 131072ull;            // + fp16 Wv copy

    if (ws_size >= WS_NEED) {
        __half* xTb  = (__half*)ws;                          // reused as OPb
        __half* Tb   = (__half*)(ws + TBE * 2);
        float*  Qs   = (float*)(ws + TBE * 4);
        float*  Ks   = Qs + (size_t)N_ * QK_ * HW_;
        float*  gate = (float*)(ws + TBE * 4 + 4718592);
        __half* Wvh  = (__half*)(ws + WS_NEED);
        // psum/pmax alias Qs/Ks (dead after ccca_col2)
        ccca_rowf<<<N_ * H_, 256, 0, stream>>>(x, Wq, Wk, Qs, Ks, xTb, Tb);
        ccca_col2<<<N_ * W_, 256, 0, stream>>>(Qs, Ks, xTb, Tb);
        if (ws_size >= WS_NEED2) {
            ccca_cvtwv<<<64, 256, 0, stream>>>(Wv, Wvh);
            ccca_wvm<<<N_ * 144, 256, 0, stream>>>(Tb, Wvh, xTb, Qs, Ks);
        } else {
            ccca_wv1<<<N_ * 144, 256, 0, stream>>>(Tb, Wv, xTb, Qs, Ks);
        }
        ccca_gate2<<<N_, 256, 0, stream>>>(Qs, Ks, W1, W2, gate);
        ccca_final2<<<2048, 256, 0, stream>>>(x, xTb, gate, gama, out);
    } else {
        float* wsf = (float*)ws;
        const size_t QSZ = (size_t)N_ * QK_ * HW_;
        float* Qb   = wsf;
        float* Kb   = wsf + QSZ;
        float* avg  = wsf + 2 * QSZ;
        float* mx   = avg + N_ * C_;
        float* gate = mx + N_ * C_;
        ccca_qk  <<<N_ * 36, 256, 0, stream>>>(x, Wq, Wk, Qb, Kb);
        ccca_row <<<N_ * H_, 256, 0, stream>>>(x, Qb, Kb, out);
        ccca_col <<<N_ * W_, 256, 0, stream>>>(x, Qb, Kb, out);
        ccca_wv  <<<N_ * 144, 256, 0, stream>>>(Wv, out);
        ccca_pool<<<N_ * C_, 256, 0, stream>>>(out, avg, mx);
        ccca_gate<<<N_, 256, 0, stream>>>(avg, mx, W1, W2, gate);
        ccca_final<<<2048, 256, 0, stream>>>(x, gate, gama, out);
    }
}

// Round 4
// 701.816 us; speedup vs baseline: 3.0430x; 1.0837x over previous
//
#include <hip/hip_runtime.h>
#include <hip/hip_fp16.h>

#define N_  16
#define C_  256
#define H_  96
#define W_  96
#define HW_ 9216
#define QK_ 4

struct alignas(8) h4 { __half2 a, b; };

__device__ inline void h4_unpack(h4 v, float* f) {
    float2 lo = __half22float2(v.a), hi = __half22float2(v.b);
    f[0] = lo.x; f[1] = lo.y; f[2] = hi.x; f[3] = hi.y;
}
__device__ inline h4 h4_pack(float a, float b, float c, float d) {
    h4 r; r.a = __floats2half2_rn(a, b); r.b = __floats2half2_rn(c, d); return r;
}

typedef __attribute__((ext_vector_type(8))) _Float16 f16x8;
typedef __attribute__((ext_vector_type(4))) float    f32x4;

// ===========================================================================
// FAST PATH
// ===========================================================================

// K0: stream x once -> Q,K fp32 [n][4][h][w]  AND  xP[n][g/8][w][c][g%8] fp16
// Block = (n, g-chunk of 8). 192 threads: w = t%96, gsub = t/96 (4 g's each).
__global__ __launch_bounds__(192) void ccca_qkt(
    const float* __restrict__ x, const float* __restrict__ Wq, const float* __restrict__ Wk,
    __half* __restrict__ xP, float* __restrict__ Qs, float* __restrict__ Ks)
{
    __shared__ float sW[8][C_];
    int t = threadIdx.x;
    int n = blockIdx.x / 12, gt = blockIdx.x % 12;
    for (int i = t; i < 8 * C_; i += 192)
        sW[i / C_][i % C_] = (i < 4 * C_) ? Wq[i] : Wk[i - 4 * C_];
    __syncthreads();
    int w = t % 96, gsub = t / 96;
    float accQ[4][4], accK[4][4];
    #pragma unroll
    for (int k = 0; k < 4; ++k)
        #pragma unroll
        for (int q = 0; q < 4; ++q) { accQ[k][q] = 0.f; accK[k][q] = 0.f; }
    const float* xb = x + (size_t)n * C_ * HW_ + (size_t)(gt * 8 + gsub * 4) * W_ + w;
    __half* xpd = xP + (((size_t)n * 12 + gt) * W_ + w) * 2048 + gsub * 4;
    for (int c = 0; c < C_; ++c) {
        float xv[4];
        #pragma unroll
        for (int k = 0; k < 4; ++k) xv[k] = xb[(size_t)c * HW_ + k * W_];
        *(h4*)(xpd + (size_t)c * 8) = h4_pack(xv[0], xv[1], xv[2], xv[3]);
        #pragma unroll
        for (int q = 0; q < QK_; ++q) {
            float wq = sW[q][c], wk = sW[4 + q][c];
            #pragma unroll
            for (int k = 0; k < 4; ++k) {
                accQ[k][q] = fmaf(wq, xv[k], accQ[k][q]);
                accK[k][q] = fmaf(wk, xv[k], accK[k][q]);
            }
        }
    }
    #pragma unroll
    for (int k = 0; k < 4; ++k) {
        int g = gt * 8 + gsub * 4 + k;
        #pragma unroll
        for (int q = 0; q < QK_; ++q) {
            Qs[(((size_t)n * QK_ + q) * H_ + g) * W_ + w] = accQ[k][q];
            Ks[(((size_t)n * QK_ + q) * H_ + g) * W_ + w] = accK[k][q];
        }
    }
}

// K1: per (n,h): scores+softmax (VALU, conflict-free layouts), T1 via MFMA.
// Writes Tb[n][px][c] fp16.
__global__ __launch_bounds__(256) void ccca_rowm(
    const float* __restrict__ x, const float* __restrict__ Qs, const float* __restrict__ Ks,
    __half* __restrict__ Tb)
{
    __shared__ __half Xs[C_][104];     // [c][v], 208B row stride (16B mult)
    __shared__ __half A1[W_][104];     // [w][v]
    __shared__ float sQ[QK_][W_], sK[QK_][W_];
    int t = threadIdx.x;
    int n = blockIdx.x / H_, h = blockIdx.x % H_;
    const float* xb = x + (size_t)n * C_ * HW_ + (size_t)h * W_;
    for (int i = t; i < C_ * 24; i += 256) {
        int c = i / 24, v4 = (i % 24) * 4;
        float4 v = *(const float4*)(xb + (size_t)c * HW_ + v4);
        *(h4*)&Xs[c][v4] = h4_pack(v.x, v.y, v.z, v.w);
    }
    for (int i = t; i < 2 * QK_ * W_; i += 256) {
        int sel = i / (QK_ * W_), r = i % (QK_ * W_);
        int q = r / W_, w = r % W_;
        float v = (sel ? Ks : Qs)[(((size_t)n * QK_ + q) * H_ + h) * W_ + w];
        if (sel) sK[q][w] = v; else sQ[q][w] = v;
    }
    __syncthreads();
    for (int i = t; i < W_ * W_; i += 256) {
        int w = i / W_, v = i % W_;
        float s = 0.f;
        #pragma unroll
        for (int q = 0; q < QK_; ++q) s = fmaf(sQ[q][w], sK[q][v], s);
        A1[w][v] = __float2half(s);
    }
    __syncthreads();
    if (t < W_) {
        float m = -1e30f;
        for (int v = 0; v < W_; ++v) m = fmaxf(m, __half2float(A1[t][v]));
        float sum = 0.f;
        for (int v = 0; v < W_; ++v) {
            float e = __expf(__half2float(A1[t][v]) - m);
            sum += e; A1[t][v] = __float2half(e);
        }
        float inv = 1.f / sum;
        for (int v = 0; v < W_; ++v)
            A1[t][v] = __float2half(__half2float(A1[t][v]) * inv);
    }
    __syncthreads();
    // T1[c][w] = sum_v Xs[c][v] * A1[w][v]
    int wd = t >> 6, lane = t & 63, ln15 = lane & 15, kg = lane >> 4;
    f32x4 acc[4][6];
    #pragma unroll
    for (int i = 0; i < 4; ++i)
        #pragma unroll
        for (int p = 0; p < 6; ++p) acc[i][p] = (f32x4){0.f, 0.f, 0.f, 0.f};
    #pragma unroll
    for (int kk = 0; kk < 3; ++kk) {
        f16x8 a[4], b[6];
        #pragma unroll
        for (int i = 0; i < 4; ++i)
            a[i] = *(const f16x8*)&Xs[64 * wd + 16 * i + ln15][kk * 32 + kg * 8];
        #pragma unroll
        for (int p = 0; p < 6; ++p)
            b[p] = *(const f16x8*)&A1[16 * p + ln15][kk * 32 + kg * 8];
        #pragma unroll
        for (int i = 0; i < 4; ++i)
            #pragma unroll
            for (int p = 0; p < 6; ++p)
                acc[i][p] = __builtin_amdgcn_mfma_f32_16x16x32_f16(a[i], b[p], acc[i][p], 0, 0, 0);
    }
    __half* Tn = Tb + ((size_t)n * H_ + h) * W_ * C_;
    #pragma unroll
    for (int i = 0; i < 4; ++i) {
        int c0 = 64 * wd + 16 * i + 4 * kg;
        #pragma unroll
        for (int p = 0; p < 6; ++p) {
            int w = 16 * p + ln15;
            *(h4*)(Tn + (size_t)w * C_ + c0) =
                h4_pack(acc[i][p][0], acc[i][p][1], acc[i][p][2], acc[i][p][3]);
        }
    }
}

// K2: per (n,w): col scores+softmax, T2 via MFMA, RMW into Tb.
__global__ __launch_bounds__(256) void ccca_colm(
    const __half* __restrict__ xP, const float* __restrict__ Qs, const float* __restrict__ Ks,
    __half* __restrict__ Tb)
{
    __shared__ __half Xs[C_][104];     // [c][g]
    __shared__ __half A2[H_][104];     // [h][g]
    __shared__ float sQ[QK_][H_], sK[QK_][H_];
    int t = threadIdx.x;
    int n = blockIdx.x / W_, w = blockIdx.x % W_;
    for (int i = t; i < 12 * C_; i += 256) {
        int gb = i >> 8, c = i & 255;
        f16x8 v = *(const f16x8*)(xP + (((size_t)n * 12 + gb) * W_ + w) * 2048 + (size_t)c * 8);
        *(f16x8*)&Xs[c][gb * 8] = v;
    }
    for (int i = t; i < 2 * QK_ * H_; i += 256) {
        int sel = i / (QK_ * H_), r = i % (QK_ * H_);
        int q = r / H_, g = r % H_;
        float v = (sel ? Ks : Qs)[(((size_t)n * QK_ + q) * H_ + g) * W_ + w];
        if (sel) sK[q][g] = v; else sQ[q][g] = v;
    }
    __syncthreads();
    for (int i = t; i < H_ * H_; i += 256) {
        int hh = i / H_, g = i % H_;
        float s = 0.f;
        #pragma unroll
        for (int q = 0; q < QK_; ++q) s = fmaf(sQ[q][hh], sK[q][g], s);
        A2[hh][g] = __float2half(s);
    }
    __syncthreads();
    if (t < H_) {
        float m = -1e30f;
        for (int g = 0; g < H_; ++g) m = fmaxf(m, __half2float(A2[t][g]));
        float sum = 0.f;
        for (int g = 0; g < H_; ++g) {
            float e = __expf(__half2float(A2[t][g]) - m);
            sum += e; A2[t][g] = __float2half(e);
        }
        float inv = 1.f / sum;
        for (int g = 0; g < H_; ++g)
            A2[t][g] = __float2half(__half2float(A2[t][g]) * inv);
    }
    __syncthreads();
    // T2[h][c] = sum_g A2[h][g] * Xs[c][g]
    int wd = t >> 6, lane = t & 63, ln15 = lane & 15, kg = lane >> 4;
    f32x4 acc[6][4];
    #pragma unroll
    for (int i = 0; i < 6; ++i)
        #pragma unroll
        for (int p = 0; p < 4; ++p) acc[i][p] = (f32x4){0.f, 0.f, 0.f, 0.f};
    #pragma unroll
    for (int kk = 0; kk < 3; ++kk) {
        f16x8 a[6], b[4];
        #pragma unroll
        for (int i = 0; i < 6; ++i)
            a[i] = *(const f16x8*)&A2[16 * i + ln15][kk * 32 + kg * 8];
        #pragma unroll
        for (int p = 0; p < 4; ++p)
            b[p] = *(const f16x8*)&Xs[64 * wd + 16 * p + ln15][kk * 32 + kg * 8];
        #pragma unroll
        for (int i = 0; i < 6; ++i)
            #pragma unroll
            for (int p = 0; p < 4; ++p)
                acc[i][p] = __builtin_amdgcn_mfma_f32_16x16x32_f16(a[i], b[p], acc[i][p], 0, 0, 0);
    }
    __half* Tn = Tb + (size_t)n * HW_ * C_;
    #pragma unroll
    for (int i = 0; i < 6; ++i)
        #pragma unroll
        for (int p = 0; p < 4; ++p) {
            int c = 64 * wd + 16 * p + ln15;
            #pragma unroll
            for (int r = 0; r < 4; ++r) {
                int hh = 16 * i + 4 * kg + r;
                __half* ptr = Tn + ((size_t)hh * W_ + w) * C_ + c;
                *ptr = __float2half(__half2float(*ptr) + acc[i][p][r]);
            }
        }
}

// K2.5: convert Wv fp32 -> fp16
__global__ __launch_bounds__(256) void ccca_cvtwv(
    const float* __restrict__ Wv, __half* __restrict__ Wvh)
{
    int gid = blockIdx.x * 256 + threadIdx.x;
    float4 v = ((const float4*)Wv)[gid];
    ((h4*)Wvh)[gid] = h4_pack(v.x, v.y, v.z, v.w);
}

// K3 (MFMA): OPb[n][c][px] = sum_o Wvh[c][o] * Tb[n][px][o]; fused partial pools.
__global__ __launch_bounds__(256) void ccca_wvm(
    const __half* __restrict__ Tb, const __half* __restrict__ Wvh,
    __half* __restrict__ OPb, float* __restrict__ psum, float* __restrict__ pmax)
{
    int t = threadIdx.x;
    int wd = t >> 6, lane = t & 63;
    int ln15 = lane & 15, kg = lane >> 4;
    int n = blockIdx.x / 144, tile = blockIdx.x % 144;

    const _Float16* Ab = (const _Float16*)Wvh + (size_t)(64 * wd + ln15) * C_ + kg * 8;
    const _Float16* Bb = (const _Float16*)Tb +
                         ((size_t)n * HW_ + tile * 64 + ln15) * C_ + kg * 8;

    f32x4 acc[4][4];
    #pragma unroll
    for (int i = 0; i < 4; ++i)
        #pragma unroll
        for (int p = 0; p < 4; ++p) acc[i][p] = (f32x4){0.f, 0.f, 0.f, 0.f};

    #pragma unroll
    for (int kk = 0; kk < 8; ++kk) {
        f16x8 a[4], b[4];
        #pragma unroll
        for (int i = 0; i < 4; ++i)
            a[i] = *(const f16x8*)(Ab + (size_t)i * 16 * C_ + kk * 32);
        #pragma unroll
        for (int p = 0; p < 4; ++p)
            b[p] = *(const f16x8*)(Bb + (size_t)p * 16 * C_ + kk * 32);
        #pragma unroll
        for (int i = 0; i < 4; ++i)
            #pragma unroll
            for (int p = 0; p < 4; ++p)
                acc[i][p] = __builtin_amdgcn_mfma_f32_16x16x32_f16(a[i], b[p], acc[i][p], 0, 0, 0);
    }

    __half* dst = OPb + (size_t)n * C_ * HW_;
    #pragma unroll
    for (int i = 0; i < 4; ++i) {
        #pragma unroll
        for (int r = 0; r < 4; ++r) {
            int c = 64 * wd + 16 * i + 4 * kg + r;
            #pragma unroll
            for (int p = 0; p < 4; ++p) {
                int px = tile * 64 + 16 * p + ln15;
                dst[(size_t)c * HW_ + px] = __float2half(acc[i][p][r]);
            }
        }
    }

    #pragma unroll
    for (int i = 0; i < 4; ++i) {
        float ps[4] = {0.f, 0.f, 0.f, 0.f};
        float pm[4] = {-1e30f, -1e30f, -1e30f, -1e30f};
        #pragma unroll
        for (int p = 0; p < 4; ++p)
            #pragma unroll
            for (int r = 0; r < 4; ++r) {
                ps[r] += acc[i][p][r];
                pm[r] = fmaxf(pm[r], acc[i][p][r]);
            }
        #pragma unroll
        for (int m = 1; m <= 8; m <<= 1)
            #pragma unroll
            for (int r = 0; r < 4; ++r) {
                ps[r] += __shfl_xor(ps[r], m);
                pm[r] = fmaxf(pm[r], __shfl_xor(pm[r], m));
            }
        if (ln15 == 0) {
            size_t base = ((size_t)n * 144 + tile) * C_ + 64 * wd + 16 * i + 4 * kg;
            #pragma unroll
            for (int r = 0; r < 4; ++r) { psum[base + r] = ps[r]; pmax[base + r] = pm[r]; }
        }
    }
}

// K4: reduce partials + SE MLP -> gate[n][c]
__global__ __launch_bounds__(256) void ccca_gate2(
    const float* __restrict__ psum, const float* __restrict__ pmax,
    const float* __restrict__ W1, const float* __restrict__ W2,
    float* __restrict__ gate)
{
    __shared__ float sa[C_], sm[C_], hs[C_];
    int n = blockIdx.x, t = threadIdx.x;
    float s = 0.f, m = -1e30f;
    for (int i = 0; i < 144; ++i) {
        s += psum[((size_t)n * 144 + i) * C_ + t];
        m = fmaxf(m, pmax[((size_t)n * 144 + i) * C_ + t]);
    }
    sa[t] = s * (1.f / 9216.f);
    sm[t] = m;
    __syncthreads();
    const float* w1r = W1 + (size_t)t * C_;
    float aa = 0.f, am = 0.f;
    for (int i = 0; i < C_; ++i) { float wv = w1r[i]; aa = fmaf(wv, sa[i], aa); am = fmaf(wv, sm[i], am); }
    hs[t] = fmaxf(aa, 0.f) + fmaxf(am, 0.f);
    __syncthreads();
    const float* w2r = W2 + (size_t)t * C_;
    float g = 0.f;
    for (int i = 0; i < C_; ++i) g = fmaf(w2r[i], hs[i], g);
    gate[n * C_ + t] = 1.f / (1.f + __expf(-g));
}

// K5: out = x + gama*gate*out_pre (elementwise)
__global__ __launch_bounds__(256) void ccca_final2(
    const float* __restrict__ x, const __half* __restrict__ OPb,
    const float* __restrict__ gate, const float* __restrict__ gama,
    float* __restrict__ out)
{
    float g0 = gama[0];
    const size_t total = (size_t)N_ * C_ * HW_ / 4;
    for (size_t i = (size_t)blockIdx.x * 256 + threadIdx.x; i < total; i += (size_t)gridDim.x * 256) {
        float4 xv = ((const float4*)x)[i];
        float ov[4];
        h4_unpack(((const h4*)OPb)[i], ov);
        size_t nc = (i * 4) / HW_;
        float sc = g0 * gate[nc];
        float4 r;
        r.x = fmaf(sc, ov[0], xv.x);
        r.y = fmaf(sc, ov[1], xv.y);
        r.z = fmaf(sc, ov[2], xv.z);
        r.w = fmaf(sc, ov[3], xv.w);
        ((float4*)out)[i] = r;
    }
}

// ===========================================================================
// FALLBACK PATH (round-1 kernels, proven correct; runs only if ws too small)
// ===========================================================================

__global__ __launch_bounds__(256) void ccca_qk(
    const float* __restrict__ x, const float* __restrict__ Wq,
    const float* __restrict__ Wk, float* __restrict__ Qo, float* __restrict__ Ko)
{
    __shared__ float sWq[QK_ * C_];
    __shared__ float sWk[QK_ * C_];
    int t = threadIdx.x;
    for (int i = t; i < QK_ * C_; i += 256) { sWq[i] = Wq[i]; sWk[i] = Wk[i]; }
    __syncthreads();
    int n = blockIdx.x / 36;
    int p = (blockIdx.x % 36) * 256 + t;
    const float* xp = x + (size_t)n * C_ * HW_ + p;
    float qa[QK_] = {0.f, 0.f, 0.f, 0.f};
    float ka[QK_] = {0.f, 0.f, 0.f, 0.f};
    for (int c = 0; c < C_; ++c) {
        float v = xp[(size_t)c * HW_];
        #pragma unroll
        for (int q = 0; q < QK_; ++q) {
            qa[q] = fmaf(v, sWq[q * C_ + c], qa[q]);
            ka[q] = fmaf(v, sWk[q * C_ + c], ka[q]);
        }
    }
    size_t base = (size_t)n * QK_ * HW_ + p;
    #pragma unroll
    for (int q = 0; q < QK_; ++q) { Qo[base + q * HW_] = qa[q]; Ko[base + q * HW_] = ka[q]; }
}

__global__ __launch_bounds__(256) void ccca_row(
    const float* __restrict__ x, const float* __restrict__ Qw,
    const float* __restrict__ Kw, float* __restrict__ out)
{
    __shared__ float sQ[QK_][W_];
    __shared__ float sK[QK_][W_];
    __shared__ float A[W_][W_ + 1];
    __shared__ float Xs[64][W_ + 1];
    int t = threadIdx.x;
    int n = blockIdx.x / H_;
    int h = blockIdx.x % H_;
    for (int i = t; i < QK_ * W_; i += 256) {
        int q = i / W_, w = i % W_;
        size_t off = ((size_t)n * QK_ + q) * HW_ + h * W_ + w;
        sQ[q][w] = Qw[off];
        sK[q][w] = Kw[off];
    }
    __syncthreads();
    for (int i = t; i < W_ * W_; i += 256) {
        int w = i / W_, v = i % W_;
        float s = 0.f;
        #pragma unroll
        for (int q = 0; q < QK_; ++q) s = fmaf(sQ[q][w], sK[q][v], s);
        A[w][v] = s;
    }
    __syncthreads();
    if (t < W_) {
        float m = -1e30f;
        for (int v = 0; v < W_; ++v) m = fmaxf(m, A[t][v]);
        float sum = 0.f;
        for (int v = 0; v < W_; ++v) { float e = __expf(A[t][v] - m); A[t][v] = e; sum += e; }
        float inv = 1.f / sum;
        for (int v = 0; v < W_; ++v) A[t][v] *= inv;
    }
    __syncthreads();
    int to = t >> 4, tw = t & 15;
    for (int ot = 0; ot < 4; ++ot) {
        for (int i = t; i < 64 * W_ / 4; i += 256) {
            int f = i * 4;
            int o = f / W_, v = f % W_;
            float4 val = *(const float4*)(x + (((size_t)n * C_ + ot * 64 + o) * H_ + h) * W_ + v);
            Xs[o][v] = val.x; Xs[o][v + 1] = val.y; Xs[o][v + 2] = val.z; Xs[o][v + 3] = val.w;
        }
        __syncthreads();
        float acc[4][6];
        #pragma unroll
        for (int i = 0; i < 4; ++i)
            #pragma unroll
            for (int j = 0; j < 6; ++j) acc[i][j] = 0.f;
        for (int v = 0; v < W_; ++v) {
            float xr[4], ar[6];
            #pragma unroll
            for (int i = 0; i < 4; ++i) xr[i] = Xs[to * 4 + i][v];
            #pragma unroll
            for (int j = 0; j < 6; ++j) ar[j] = A[tw * 6 + j][v];
            #pragma unroll
            for (int i = 0; i < 4; ++i)
                #pragma unroll
                for (int j = 0; j < 6; ++j) acc[i][j] = fmaf(xr[i], ar[j], acc[i][j]);
        }
        #pragma unroll
        for (int i = 0; i < 4; ++i) {
            size_t ob = (((size_t)n * C_ + ot * 64 + to * 4 + i) * H_ + h) * W_ + tw * 6;
            #pragma unroll
            for (int j = 0; j < 6; ++j) out[ob + j] = acc[i][j];
        }
        __syncthreads();
    }
}

__global__ __launch_bounds__(256) void ccca_col(
    const float* __restrict__ x, const float* __restrict__ Qw,
    const float* __restrict__ Kw, float* __restrict__ out)
{
    __shared__ float sQ[QK_][H_];
    __shared__ float sK[QK_][H_];
    __shared__ float A[H_][H_ + 1];
    __shared__ float Xc[64][H_ + 1];
    int t = threadIdx.x;
    int n = blockIdx.x / W_;
    int w = blockIdx.x % W_;
    for (int i = t; i < QK_ * H_; i += 256) {
        int q = i / H_, hh = i % H_;
        size_t off = ((size_t)n * QK_ + q) * HW_ + hh * W_ + w;
        sQ[q][hh] = Qw[off];
        sK[q][hh] = Kw[off];
    }
    __syncthreads();
    for (int i = t; i < H_ * H_; i += 256) {
        int hh = i / H_, g = i % H_;
        float s = 0.f;
        #pragma unroll
        for (int q = 0; q < QK_; ++q) s = fmaf(sQ[q][hh], sK[q][g], s);
        A[hh][g] = s;
    }
    __syncthreads();
    if (t < H_) {
        float m = -1e30f;
        for (int g = 0; g < H_; ++g) m = fmaxf(m, A[t][g]);
        float sum = 0.f;
        for (int g = 0; g < H_; ++g) { float e = __expf(A[t][g] - m); A[t][g] = e; sum += e; }
        float inv = 1.f / sum;
        for (int g = 0; g < H_; ++g) A[t][g] *= inv;
    }
    __syncthreads();
    int to = t >> 4, th = t & 15;
    for (int ot = 0; ot < 4; ++ot) {
        for (int i = t; i < 64 * H_; i += 256) {
            int o = i / H_, g = i % H_;
            Xc[o][g] = x[(((size_t)n * C_ + ot * 64 + o) * H_ + g) * W_ + w];
        }
        __syncthreads();
        float acc[4][6];
        #pragma unroll
        for (int i = 0; i < 4; ++i)
            #pragma unroll
            for (int j = 0; j < 6; ++j) acc[i][j] = 0.f;
        for (int g = 0; g < H_; ++g) {
            float xr[4], ar[6];
            #pragma unroll
            for (int i = 0; i < 4; ++i) xr[i] = Xc[to * 4 + i][g];
            #pragma unroll
            for (int j = 0; j < 6; ++j) ar[j] = A[th * 6 + j][g];
            #pragma unroll
            for (int i = 0; i < 4; ++i)
                #pragma unroll
                for (int j = 0; j < 6; ++j) acc[i][j] = fmaf(xr[i], ar[j], acc[i][j]);
        }
        #pragma unroll
        for (int i = 0; i < 4; ++i)
            #pragma unroll
            for (int j = 0; j < 6; ++j) {
                size_t ob = (((size_t)n * C_ + ot * 64 + to * 4 + i) * H_ + th * 6 + j) * W_ + w;
                out[ob] += acc[i][j];
            }
        __syncthreads();
    }
}

__global__ __launch_bounds__(256) void ccca_wv(
    const float* __restrict__ Wv, float* __restrict__ out)
{
    __shared__ float Ts[C_][64];
    int t = threadIdx.x;
    int n = blockIdx.x / 144;
    int p0 = (blockIdx.x % 144) * 64;
    float* base = out + (size_t)n * C_ * HW_ + p0;
    for (int i = t; i < C_ * 16; i += 256) {
        int o = i >> 4, p4 = (i & 15) << 2;
        *(float4*)&Ts[o][p4] = *(const float4*)(base + (size_t)o * HW_ + p4);
    }
    __syncthreads();
    int cb = t >> 4, pb = t & 15;
    float acc[16][4];
    #pragma unroll
    for (int j = 0; j < 16; ++j)
        #pragma unroll
        for (int p = 0; p < 4; ++p) acc[j][p] = 0.f;
    for (int o = 0; o < C_; o += 4) {
        float tvv[4][4];
        #pragma unroll
        for (int k = 0; k < 4; ++k) {
            float4 q = *(float4*)&Ts[o + k][pb * 4];
            tvv[k][0] = q.x; tvv[k][1] = q.y; tvv[k][2] = q.z; tvv[k][3] = q.w;
        }
        #pragma unroll
        for (int j = 0; j < 16; ++j) {
            float4 wv = *(const float4*)(Wv + (size_t)(cb * 16 + j) * C_ + o);
            float wvv[4] = {wv.x, wv.y, wv.z, wv.w};
            #pragma unroll
            for (int k = 0; k < 4; ++k)
                #pragma unroll
                for (int p = 0; p < 4; ++p)
                    acc[j][p] = fmaf(wvv[k], tvv[k][p], acc[j][p]);
        }
    }
    #pragma unroll
    for (int j = 0; j < 16; ++j) {
        float4 r; r.x = acc[j][0]; r.y = acc[j][1]; r.z = acc[j][2]; r.w = acc[j][3];
        *(float4*)(base + (size_t)(cb * 16 + j) * HW_ + pb * 4) = r;
    }
}

__global__ __launch_bounds__(256) void ccca_pool(
    const float* __restrict__ out, float* __restrict__ avg, float* __restrict__ mx)
{
    int nc = blockIdx.x;
    const float* p = out + (size_t)nc * HW_;
    int t = threadIdx.x;
    float s = 0.f, m = -1e30f;
    for (int i = t; i < HW_; i += 256) { float v = p[i]; s += v; m = fmaxf(m, v); }
    #pragma unroll
    for (int off = 32; off > 0; off >>= 1) {
        s += __shfl_down(s, off);
        m = fmaxf(m, __shfl_down(m, off));
    }
    __shared__ float ss[4], smx[4];
    int wv = t >> 6;
    if ((t & 63) == 0) { ss[wv] = s; smx[wv] = m; }
    __syncthreads();
    if (t == 0) {
        s = ss[0] + ss[1] + ss[2] + ss[3];
        m = fmaxf(fmaxf(smx[0], smx[1]), fmaxf(smx[2], smx[3]));
        avg[nc] = s * (1.f / 9216.f);
        mx[nc] = m;
    }
}

__global__ __launch_bounds__(256) void ccca_gate(
    const float* __restrict__ avg, const float* __restrict__ mx,
    const float* __restrict__ W1, const float* __restrict__ W2,
    float* __restrict__ gate)
{
    __shared__ float sa[C_], sm[C_], hs[C_];
    int n = blockIdx.x, t = threadIdx.x;
    sa[t] = avg[n * C_ + t];
    sm[t] = mx[n * C_ + t];
    __syncthreads();
    const float* w1r = W1 + (size_t)t * C_;
    float aa = 0.f, am = 0.f;
    for (int i = 0; i < C_; ++i) { float wv = w1r[i]; aa = fmaf(wv, sa[i], aa); am = fmaf(wv, sm[i], am); }
    hs[t] = fmaxf(aa, 0.f) + fmaxf(am, 0.f);
    __syncthreads();
    const float* w2r = W2 + (size_t)t * C_;
    float g = 0.f;
    for (int i = 0; i < C_; ++i) g = fmaf(w2r[i], hs[i], g);
    gate[n * C_ + t] = 1.f / (1.f + __expf(-g));
}

__global__ __launch_bounds__(256) void ccca_final(
    const float* __restrict__ x, const float* __restrict__ gate,
    const float* __restrict__ gama, float* __restrict__ out)
{
    float g0 = gama[0];
    const size_t total = (size_t)N_ * C_ * HW_ / 4;
    for (size_t i = (size_t)blockIdx.x * 256 + threadIdx.x; i < total; i += (size_t)gridDim.x * 256) {
        float4 o = ((const float4*)out)[i];
        float4 xv = ((const float4*)x)[i];
        size_t nc = (i * 4) / HW_;
        float sc = g0 * gate[nc];
        o.x = fmaf(sc, o.x, xv.x);
        o.y = fmaf(sc, o.y, xv.y);
        o.z = fmaf(sc, o.z, xv.z);
        o.w = fmaf(sc, o.w, xv.w);
        ((float4*)out)[i] = o;
    }
}

// ===========================================================================

extern "C" void kernel_launch(void* const* d_in, const int* in_sizes, int n_in,
                              void* d_out, int out_size, void* d_ws, size_t ws_size,
                              hipStream_t stream)
{
    const float* x    = (const float*)d_in[0];
    const float* Wq   = (const float*)d_in[1];
    const float* Wk   = (const float*)d_in[2];
    const float* Wv   = (const float*)d_in[3];
    const float* W1   = (const float*)d_in[4];
    const float* W2   = (const float*)d_in[5];
    const float* gama = (const float*)d_in[6];
    float* out = (float*)d_out;
    char*  ws  = (char*)d_ws;

    // ws layout (bytes):
    //   xP  @ 0           : 75,497,472   (fp16; reused as OPb by wvm)
    //   Tb  @ 75,497,472  : 75,497,472   (fp16; reused as gate after wvm)
    //   Qs  @ 150,994,944 :  2,359,296   (fp32; reused as psum)
    //   Ks  @ 153,354,240 :  2,359,296   (fp32; reused as pmax)
    //   Wvh @ 155,713,536 :    131,072   (fp16)
    const size_t WS_NEED3 = 155844608ull;   // proven ws_size >= 155,860,992

    if (ws_size >= WS_NEED3) {
        __half* xP   = (__half*)ws;
        __half* Tb   = (__half*)(ws + 75497472ull);
        float*  Qs   = (float*)(ws + 150994944ull);
        float*  Ks   = (float*)(ws + 153354240ull);
        __half* Wvh  = (__half*)(ws + 155713536ull);
        float*  psum = Qs;
        float*  pmax = Ks;
        float*  gate = (float*)Tb;
        __half* OPb  = xP;

        ccca_qkt  <<<N_ * 12, 192, 0, stream>>>(x, Wq, Wk, xP, Qs, Ks);
        ccca_cvtwv<<<64, 256, 0, stream>>>(Wv, Wvh);
        ccca_rowm <<<N_ * H_, 256, 0, stream>>>(x, Qs, Ks, Tb);
        ccca_colm <<<N_ * W_, 256, 0, stream>>>(xP, Qs, Ks, Tb);
        ccca_wvm  <<<N_ * 144, 256, 0, stream>>>(Tb, Wvh, OPb, psum, pmax);
        ccca_gate2<<<N_, 256, 0, stream>>>(psum, pmax, W1, W2, gate);
        ccca_final2<<<2048, 256, 0, stream>>>(x, OPb, gate, gama, out);
    } else {
        float* wsf = (float*)ws;
        const size_t QSZ = (size_t)N_ * QK_ * HW_;
        float* Qb   = wsf;
        float* Kb   = wsf + QSZ;
        float* avg  = wsf + 2 * QSZ;
        float* mx   = avg + N_ * C_;
        float* gate = mx + N_ * C_;
        ccca_qk  <<<N_ * 36, 256, 0, stream>>>(x, Wq, Wk, Qb, Kb);
        ccca_row <<<N_ * H_, 256, 0, stream>>>(x, Qb, Kb, out);
        ccca_col <<<N_ * W_, 256, 0, stream>>>(x, Qb, Kb, out);
        ccca_wv  <<<N_ * 144, 256, 0, stream>>>(Wv, out);
        ccca_pool<<<N_ * C_, 256, 0, stream>>>(out, avg, mx);
        ccca_gate<<<N_, 256, 0, stream>>>(avg, mx, W1, W2, gate);
        ccca_final<<<2048, 256, 0, stream>>>(x, gate, gama, out);
    }
}

// Round 6
// 698.743 us; speedup vs baseline: 3.0564x; 1.0044x over previous
//
#include <hip/hip_runtime.h>
#include <hip/hip_fp16.h>

#define N_  16
#define C_  256
#define H_  96
#define W_  96
#define HW_ 9216
#define QK_ 4
#define QSZ_ 589824   // N_*QK_*HW_

struct alignas(8) h4 { __half2 a, b; };

__device__ inline void h4_unpack(h4 v, float* f) {
    float2 lo = __half22float2(v.a), hi = __half22float2(v.b);
    f[0] = lo.x; f[1] = lo.y; f[2] = hi.x; f[3] = hi.y;
}
__device__ inline h4 h4_pack(float a, float b, float c, float d) {
    h4 r; r.a = __floats2half2_rn(a, b); r.b = __floats2half2_rn(c, d); return r;
}

typedef __attribute__((ext_vector_type(8))) _Float16 f16x8;
typedef __attribute__((ext_vector_type(4))) float    f32x4;

// ===========================================================================
// FAST PATH
// ===========================================================================

// K0: stream x -> xP[n][g/8][w][c][g%8] fp16 + PARTIAL Q,K (c-chunk of 32).
// Block = (n, g-chunk of 8, c-chunk cc of 32). 16*12*8 = 1536 blocks.
__global__ __launch_bounds__(192) void ccca_qkt(
    const float* __restrict__ x, const float* __restrict__ Wq, const float* __restrict__ Wk,
    __half* __restrict__ xP, float* __restrict__ Qp, float* __restrict__ Kp)
{
    __shared__ float sW[8][32];
    int t = threadIdx.x;
    int blk = blockIdx.x;
    int n = blk / 96;
    int rem = blk % 96;
    int gt = rem / 8, cc = rem % 8;
    int c0 = cc * 32;
    for (int i = t; i < 8 * 32; i += 192) {
        int r = i / 32, c = i % 32;
        sW[r][c] = (r < 4) ? Wq[r * C_ + c0 + c] : Wk[(r - 4) * C_ + c0 + c];
    }
    __syncthreads();
    int w = t % 96, gsub = t / 96;
    float accQ[4][4], accK[4][4];
    #pragma unroll
    for (int k = 0; k < 4; ++k)
        #pragma unroll
        for (int q = 0; q < 4; ++q) { accQ[k][q] = 0.f; accK[k][q] = 0.f; }
    const float* xb = x + (size_t)n * C_ * HW_ + (size_t)c0 * HW_
                        + (size_t)(gt * 8 + gsub * 4) * W_ + w;
    __half* xpd = xP + (((size_t)n * 12 + gt) * W_ + w) * 2048 + (size_t)c0 * 8 + gsub * 4;
    #pragma unroll 2
    for (int c = 0; c < 32; ++c) {
        float xv[4];
        #pragma unroll
        for (int k = 0; k < 4; ++k) xv[k] = xb[(size_t)c * HW_ + k * W_];
        *(h4*)(xpd + (size_t)c * 8) = h4_pack(xv[0], xv[1], xv[2], xv[3]);
        #pragma unroll
        for (int q = 0; q < QK_; ++q) {
            float wq = sW[q][c], wk = sW[4 + q][c];
            #pragma unroll
            for (int k = 0; k < 4; ++k) {
                accQ[k][q] = fmaf(wq, xv[k], accQ[k][q]);
                accK[k][q] = fmaf(wk, xv[k], accK[k][q]);
            }
        }
    }
    size_t pbase = (size_t)cc * QSZ_;
    #pragma unroll
    for (int k = 0; k < 4; ++k) {
        int g = gt * 8 + gsub * 4 + k;
        #pragma unroll
        for (int q = 0; q < QK_; ++q) {
            size_t off = (((size_t)n * QK_ + q) * H_ + g) * W_ + w;
            Qp[pbase + off] = accQ[k][q];
            Kp[pbase + off] = accK[k][q];
        }
    }
}

// K0.5: reduce the 8 c-chunk partials -> Qs, Ks
__global__ __launch_bounds__(256) void ccca_qkred(
    const float* __restrict__ Qp, const float* __restrict__ Kp,
    float* __restrict__ Qs, float* __restrict__ Ks)
{
    size_t i = (size_t)blockIdx.x * 256 + threadIdx.x;   // 2304 blocks = QSZ_/256
    float q = 0.f, k = 0.f;
    #pragma unroll
    for (int cc = 0; cc < 8; ++cc) {
        q += Qp[(size_t)cc * QSZ_ + i];
        k += Kp[(size_t)cc * QSZ_ + i];
    }
    Qs[i] = q;
    Ks[i] = k;
}

// K1: per (n,h): scores+softmax, T1 via MFMA. Writes Tb[n][px][c] fp16.
__global__ __launch_bounds__(256) void ccca_rowm(
    const float* __restrict__ x, const float* __restrict__ Qs, const float* __restrict__ Ks,
    __half* __restrict__ Tb)
{
    __shared__ __half Xs[C_][104];     // [c][v]
    __shared__ __half A1[W_][104];     // [w][v]
    __shared__ float sQ[QK_][W_], sK[QK_][W_];
    int t = threadIdx.x;
    int n = blockIdx.x / H_, h = blockIdx.x % H_;
    const float* xb = x + (size_t)n * C_ * HW_ + (size_t)h * W_;
    for (int i = t; i < C_ * 24; i += 256) {
        int c = i / 24, v4 = (i % 24) * 4;
        float4 v = *(const float4*)(xb + (size_t)c * HW_ + v4);
        *(h4*)&Xs[c][v4] = h4_pack(v.x, v.y, v.z, v.w);
    }
    for (int i = t; i < 2 * QK_ * W_; i += 256) {
        int sel = i / (QK_ * W_), r = i % (QK_ * W_);
        int q = r / W_, w = r % W_;
        float v = (sel ? Ks : Qs)[(((size_t)n * QK_ + q) * H_ + h) * W_ + w];
        if (sel) sK[q][w] = v; else sQ[q][w] = v;
    }
    __syncthreads();
    for (int i = t; i < W_ * W_; i += 256) {
        int w = i / W_, v = i % W_;
        float s = 0.f;
        #pragma unroll
        for (int q = 0; q < QK_; ++q) s = fmaf(sQ[q][w], sK[q][v], s);
        A1[w][v] = __float2half(s);
    }
    __syncthreads();
    if (t < W_) {
        float m = -1e30f;
        for (int v = 0; v < W_; ++v) m = fmaxf(m, __half2float(A1[t][v]));
        float sum = 0.f;
        for (int v = 0; v < W_; ++v) {
            float e = __expf(__half2float(A1[t][v]) - m);
            sum += e; A1[t][v] = __float2half(e);
        }
        float inv = 1.f / sum;
        for (int v = 0; v < W_; ++v)
            A1[t][v] = __float2half(__half2float(A1[t][v]) * inv);
    }
    __syncthreads();
    int wd = t >> 6, lane = t & 63, ln15 = lane & 15, kg = lane >> 4;
    f32x4 acc[4][6];
    #pragma unroll
    for (int i = 0; i < 4; ++i)
        #pragma unroll
        for (int p = 0; p < 6; ++p) acc[i][p] = (f32x4){0.f, 0.f, 0.f, 0.f};
    #pragma unroll
    for (int kk = 0; kk < 3; ++kk) {
        f16x8 a[4], b[6];
        #pragma unroll
        for (int i = 0; i < 4; ++i)
            a[i] = *(const f16x8*)&Xs[64 * wd + 16 * i + ln15][kk * 32 + kg * 8];
        #pragma unroll
        for (int p = 0; p < 6; ++p)
            b[p] = *(const f16x8*)&A1[16 * p + ln15][kk * 32 + kg * 8];
        #pragma unroll
        for (int i = 0; i < 4; ++i)
            #pragma unroll
            for (int p = 0; p < 6; ++p)
                acc[i][p] = __builtin_amdgcn_mfma_f32_16x16x32_f16(a[i], b[p], acc[i][p], 0, 0, 0);
    }
    __half* Tn = Tb + ((size_t)n * H_ + h) * W_ * C_;
    #pragma unroll
    for (int i = 0; i < 4; ++i) {
        int c0 = 64 * wd + 16 * i + 4 * kg;
        #pragma unroll
        for (int p = 0; p < 6; ++p) {
            int w = 16 * p + ln15;
            *(h4*)(Tn + (size_t)w * C_ + c0) =
                h4_pack(acc[i][p][0], acc[i][p][1], acc[i][p][2], acc[i][p][3]);
        }
    }
}

// K2: per (n,w): col scores+softmax, T2 via MFMA, RMW into Tb.
__global__ __launch_bounds__(256) void ccca_colm(
    const __half* __restrict__ xP, const float* __restrict__ Qs, const float* __restrict__ Ks,
    __half* __restrict__ Tb)
{
    __shared__ __half Xs[C_][104];     // [c][g]
    __shared__ __half A2[H_][104];     // [h][g]
    __shared__ float sQ[QK_][H_], sK[QK_][H_];
    int t = threadIdx.x;
    int n = blockIdx.x / W_, w = blockIdx.x % W_;
    for (int i = t; i < 12 * C_; i += 256) {
        int gb = i >> 8, c = i & 255;
        f16x8 v = *(const f16x8*)(xP + (((size_t)n * 12 + gb) * W_ + w) * 2048 + (size_t)c * 8);
        *(f16x8*)&Xs[c][gb * 8] = v;
    }
    for (int i = t; i < 2 * QK_ * H_; i += 256) {
        int sel = i / (QK_ * H_), r = i % (QK_ * H_);
        int q = r / H_, g = r % H_;
        float v = (sel ? Ks : Qs)[(((size_t)n * QK_ + q) * H_ + g) * W_ + w];
        if (sel) sK[q][g] = v; else sQ[q][g] = v;
    }
    __syncthreads();
    for (int i = t; i < H_ * H_; i += 256) {
        int hh = i / H_, g = i % H_;
        float s = 0.f;
        #pragma unroll
        for (int q = 0; q < QK_; ++q) s = fmaf(sQ[q][hh], sK[q][g], s);
        A2[hh][g] = __float2half(s);
    }
    __syncthreads();
    if (t < H_) {
        float m = -1e30f;
        for (int g = 0; g < H_; ++g) m = fmaxf(m, __half2float(A2[t][g]));
        float sum = 0.f;
        for (int g = 0; g < H_; ++g) {
            float e = __expf(__half2float(A2[t][g]) - m);
            sum += e; A2[t][g] = __float2half(e);
        }
        float inv = 1.f / sum;
        for (int g = 0; g < H_; ++g)
            A2[t][g] = __float2half(__half2float(A2[t][g]) * inv);
    }
    __syncthreads();
    int wd = t >> 6, lane = t & 63, ln15 = lane & 15, kg = lane >> 4;
    f32x4 acc[6][4];
    #pragma unroll
    for (int i = 0; i < 6; ++i)
        #pragma unroll
        for (int p = 0; p < 4; ++p) acc[i][p] = (f32x4){0.f, 0.f, 0.f, 0.f};
    #pragma unroll
    for (int kk = 0; kk < 3; ++kk) {
        f16x8 a[6], b[4];
        #pragma unroll
        for (int i = 0; i < 6; ++i)
            a[i] = *(const f16x8*)&A2[16 * i + ln15][kk * 32 + kg * 8];
        #pragma unroll
        for (int p = 0; p < 4; ++p)
            b[p] = *(const f16x8*)&Xs[64 * wd + 16 * p + ln15][kk * 32 + kg * 8];
        #pragma unroll
        for (int i = 0; i < 6; ++i)
            #pragma unroll
            for (int p = 0; p < 4; ++p)
                acc[i][p] = __builtin_amdgcn_mfma_f32_16x16x32_f16(a[i], b[p], acc[i][p], 0, 0, 0);
    }
    __half* Tn = Tb + (size_t)n * HW_ * C_;
    #pragma unroll
    for (int i = 0; i < 6; ++i)
        #pragma unroll
        for (int p = 0; p < 4; ++p) {
            int c = 64 * wd + 16 * p + ln15;
            #pragma unroll
            for (int r = 0; r < 4; ++r) {
                int hh = 16 * i + 4 * kg + r;
                __half* ptr = Tn + ((size_t)hh * W_ + w) * C_ + c;
                *ptr = __float2half(__half2float(*ptr) + acc[i][p][r]);
            }
        }
}

// K2.5: convert Wv fp32 -> fp16
__global__ __launch_bounds__(256) void ccca_cvtwv(
    const float* __restrict__ Wv, __half* __restrict__ Wvh)
{
    int gid = blockIdx.x * 256 + threadIdx.x;
    float4 v = ((const float4*)Wv)[gid];
    ((h4*)Wvh)[gid] = h4_pack(v.x, v.y, v.z, v.w);
}

// K3 (MFMA): OPb[n][c][px] = sum_o Wvh[c][o] * Tb[n][px][o]; fused partial pools.
__global__ __launch_bounds__(256) void ccca_wvm(
    const __half* __restrict__ Tb, const __half* __restrict__ Wvh,
    __half* __restrict__ OPb, float* __restrict__ psum, float* __restrict__ pmax)
{
    int t = threadIdx.x;
    int wd = t >> 6, lane = t & 63;
    int ln15 = lane & 15, kg = lane >> 4;
    int n = blockIdx.x / 144, tile = blockIdx.x % 144;

    const _Float16* Ab = (const _Float16*)Wvh + (size_t)(64 * wd + ln15) * C_ + kg * 8;
    const _Float16* Bb = (const _Float16*)Tb +
                         ((size_t)n * HW_ + tile * 64 + ln15) * C_ + kg * 8;

    f32x4 acc[4][4];
    #pragma unroll
    for (int i = 0; i < 4; ++i)
        #pragma unroll
        for (int p = 0; p < 4; ++p) acc[i][p] = (f32x4){0.f, 0.f, 0.f, 0.f};

    #pragma unroll
    for (int kk = 0; kk < 8; ++kk) {
        f16x8 a[4], b[4];
        #pragma unroll
        for (int i = 0; i < 4; ++i)
            a[i] = *(const f16x8*)(Ab + (size_t)i * 16 * C_ + kk * 32);
        #pragma unroll
        for (int p = 0; p < 4; ++p)
            b[p] = *(const f16x8*)(Bb + (size_t)p * 16 * C_ + kk * 32);
        #pragma unroll
        for (int i = 0; i < 4; ++i)
            #pragma unroll
            for (int p = 0; p < 4; ++p)
                acc[i][p] = __builtin_amdgcn_mfma_f32_16x16x32_f16(a[i], b[p], acc[i][p], 0, 0, 0);
    }

    __half* dst = OPb + (size_t)n * C_ * HW_;
    #pragma unroll
    for (int i = 0; i < 4; ++i) {
        #pragma unroll
        for (int r = 0; r < 4; ++r) {
            int c = 64 * wd + 16 * i + 4 * kg + r;
            #pragma unroll
            for (int p = 0; p < 4; ++p) {
                int px = tile * 64 + 16 * p + ln15;
                dst[(size_t)c * HW_ + px] = __float2half(acc[i][p][r]);
            }
        }
    }

    #pragma unroll
    for (int i = 0; i < 4; ++i) {
        float ps[4] = {0.f, 0.f, 0.f, 0.f};
        float pm[4] = {-1e30f, -1e30f, -1e30f, -1e30f};
        #pragma unroll
        for (int p = 0; p < 4; ++p)
            #pragma unroll
            for (int r = 0; r < 4; ++r) {
                ps[r] += acc[i][p][r];
                pm[r] = fmaxf(pm[r], acc[i][p][r]);
            }
        #pragma unroll
        for (int m = 1; m <= 8; m <<= 1)
            #pragma unroll
            for (int r = 0; r < 4; ++r) {
                ps[r] += __shfl_xor(ps[r], m);
                pm[r] = fmaxf(pm[r], __shfl_xor(pm[r], m));
            }
        if (ln15 == 0) {
            size_t base = ((size_t)n * 144 + tile) * C_ + 64 * wd + 16 * i + 4 * kg;
            #pragma unroll
            for (int r = 0; r < 4; ++r) { psum[base + r] = ps[r]; pmax[base + r] = pm[r]; }
        }
    }
}

// K4: reduce partials + SE MLP -> gate[n][c]
__global__ __launch_bounds__(256) void ccca_gate2(
    const float* __restrict__ psum, const float* __restrict__ pmax,
    const float* __restrict__ W1, const float* __restrict__ W2,
    float* __restrict__ gate)
{
    __shared__ float sa[C_], sm[C_], hs[C_];
    int n = blockIdx.x, t = threadIdx.x;
    float s = 0.f, m = -1e30f;
    for (int i = 0; i < 144; ++i) {
        s += psum[((size_t)n * 144 + i) * C_ + t];
        m = fmaxf(m, pmax[((size_t)n * 144 + i) * C_ + t]);
    }
    sa[t] = s * (1.f / 9216.f);
    sm[t] = m;
    __syncthreads();
    const float* w1r = W1 + (size_t)t * C_;
    float aa = 0.f, am = 0.f;
    for (int i = 0; i < C_; ++i) { float wv = w1r[i]; aa = fmaf(wv, sa[i], aa); am = fmaf(wv, sm[i], am); }
    hs[t] = fmaxf(aa, 0.f) + fmaxf(am, 0.f);
    __syncthreads();
    const float* w2r = W2 + (size_t)t * C_;
    float g = 0.f;
    for (int i = 0; i < C_; ++i) g = fmaf(w2r[i], hs[i], g);
    gate[n * C_ + t] = 1.f / (1.f + __expf(-g));
}

// K5: out = x + gama*gate*out_pre (elementwise)
__global__ __launch_bounds__(256) void ccca_final2(
    const float* __restrict__ x, const __half* __restrict__ OPb,
    const float* __restrict__ gate, const float* __restrict__ gama,
    float* __restrict__ out)
{
    float g0 = gama[0];
    const size_t total = (size_t)N_ * C_ * HW_ / 4;
    for (size_t i = (size_t)blockIdx.x * 256 + threadIdx.x; i < total; i += (size_t)gridDim.x * 256) {
        float4 xv = ((const float4*)x)[i];
        float ov[4];
        h4_unpack(((const h4*)OPb)[i], ov);
        size_t nc = (i * 4) / HW_;
        float sc = g0 * gate[nc];
        float4 r;
        r.x = fmaf(sc, ov[0], xv.x);
        r.y = fmaf(sc, ov[1], xv.y);
        r.z = fmaf(sc, ov[2], xv.z);
        r.w = fmaf(sc, ov[3], xv.w);
        ((float4*)out)[i] = r;
    }
}

// ===========================================================================
// FALLBACK PATH (round-1 kernels, proven correct; runs only if ws too small)
// ===========================================================================

__global__ __launch_bounds__(256) void ccca_qk(
    const float* __restrict__ x, const float* __restrict__ Wq,
    const float* __restrict__ Wk, float* __restrict__ Qo, float* __restrict__ Ko)
{
    __shared__ float sWq[QK_ * C_];
    __shared__ float sWk[QK_ * C_];
    int t = threadIdx.x;
    for (int i = t; i < QK_ * C_; i += 256) { sWq[i] = Wq[i]; sWk[i] = Wk[i]; }
    __syncthreads();
    int n = blockIdx.x / 36;
    int p = (blockIdx.x % 36) * 256 + t;
    const float* xp = x + (size_t)n * C_ * HW_ + p;
    float qa[QK_] = {0.f, 0.f, 0.f, 0.f};
    float ka[QK_] = {0.f, 0.f, 0.f, 0.f};
    for (int c = 0; c < C_; ++c) {
        float v = xp[(size_t)c * HW_];
        #pragma unroll
        for (int q = 0; q < QK_; ++q) {
            qa[q] = fmaf(v, sWq[q * C_ + c], qa[q]);
            ka[q] = fmaf(v, sWk[q * C_ + c], ka[q]);
        }
    }
    size_t base = (size_t)n * QK_ * HW_ + p;
    #pragma unroll
    for (int q = 0; q < QK_; ++q) { Qo[base + q * HW_] = qa[q]; Ko[base + q * HW_] = ka[q]; }
}

__global__ __launch_bounds__(256) void ccca_row(
    const float* __restrict__ x, const float* __restrict__ Qw,
    const float* __restrict__ Kw, float* __restrict__ out)
{
    __shared__ float sQ[QK_][W_];
    __shared__ float sK[QK_][W_];
    __shared__ float A[W_][W_ + 1];
    __shared__ float Xs[64][W_ + 1];
    int t = threadIdx.x;
    int n = blockIdx.x / H_;
    int h = blockIdx.x % H_;
    for (int i = t; i < QK_ * W_; i += 256) {
        int q = i / W_, w = i % W_;
        size_t off = ((size_t)n * QK_ + q) * HW_ + h * W_ + w;
        sQ[q][w] = Qw[off];
        sK[q][w] = Kw[off];
    }
    __syncthreads();
    for (int i = t; i < W_ * W_; i += 256) {
        int w = i / W_, v = i % W_;
        float s = 0.f;
        #pragma unroll
        for (int q = 0; q < QK_; ++q) s = fmaf(sQ[q][w], sK[q][v], s);
        A[w][v] = s;
    }
    __syncthreads();
    if (t < W_) {
        float m = -1e30f;
        for (int v = 0; v < W_; ++v) m = fmaxf(m, A[t][v]);
        float sum = 0.f;
        for (int v = 0; v < W_; ++v) { float e = __expf(A[t][v] - m); A[t][v] = e; sum += e; }
        float inv = 1.f / sum;
        for (int v = 0; v < W_; ++v) A[t][v] *= inv;
    }
    __syncthreads();
    int to = t >> 4, tw = t & 15;
    for (int ot = 0; ot < 4; ++ot) {
        for (int i = t; i < 64 * W_ / 4; i += 256) {
            int f = i * 4;
            int o = f / W_, v = f % W_;
            float4 val = *(const float4*)(x + (((size_t)n * C_ + ot * 64 + o) * H_ + h) * W_ + v);
            Xs[o][v] = val.x; Xs[o][v + 1] = val.y; Xs[o][v + 2] = val.z; Xs[o][v + 3] = val.w;
        }
        __syncthreads();
        float acc[4][6];
        #pragma unroll
        for (int i = 0; i < 4; ++i)
            #pragma unroll
            for (int j = 0; j < 6; ++j) acc[i][j] = 0.f;
        for (int v = 0; v < W_; ++v) {
            float xr[4], ar[6];
            #pragma unroll
            for (int i = 0; i < 4; ++i) xr[i] = Xs[to * 4 + i][v];
            #pragma unroll
            for (int j = 0; j < 6; ++j) ar[j] = A[tw * 6 + j][v];
            #pragma unroll
            for (int i = 0; i < 4; ++i)
                #pragma unroll
                for (int j = 0; j < 6; ++j) acc[i][j] = fmaf(xr[i], ar[j], acc[i][j]);
        }
        #pragma unroll
        for (int i = 0; i < 4; ++i) {
            size_t ob = (((size_t)n * C_ + ot * 64 + to * 4 + i) * H_ + h) * W_ + tw * 6;
            #pragma unroll
            for (int j = 0; j < 6; ++j) out[ob + j] = acc[i][j];
        }
        __syncthreads();
    }
}

__global__ __launch_bounds__(256) void ccca_col(
    const float* __restrict__ x, const float* __restrict__ Qw,
    const float* __restrict__ Kw, float* __restrict__ out)
{
    __shared__ float sQ[QK_][H_];
    __shared__ float sK[QK_][H_];
    __shared__ float A[H_][H_ + 1];
    __shared__ float Xc[64][H_ + 1];
    int t = threadIdx.x;
    int n = blockIdx.x / W_;
    int w = blockIdx.x % W_;
    for (int i = t; i < QK_ * H_; i += 256) {
        int q = i / H_, hh = i % H_;
        size_t off = ((size_t)n * QK_ + q) * HW_ + hh * W_ + w;
        sQ[q][hh] = Qw[off];
        sK[q][hh] = Kw[off];
    }
    __syncthreads();
    for (int i = t; i < H_ * H_; i += 256) {
        int hh = i / H_, g = i % H_;
        float s = 0.f;
        #pragma unroll
        for (int q = 0; q < QK_; ++q) s = fmaf(sQ[q][hh], sK[q][g], s);
        A[hh][g] = s;
    }
    __syncthreads();
    if (t < H_) {
        float m = -1e30f;
        for (int g = 0; g < H_; ++g) m = fmaxf(m, A[t][g]);
        float sum = 0.f;
        for (int g = 0; g < H_; ++g) { float e = __expf(A[t][g] - m); A[t][g] = e; sum += e; }
        float inv = 1.f / sum;
        for (int g = 0; g < H_; ++g) A[t][g] *= inv;
    }
    __syncthreads();
    int to = t >> 4, th = t & 15;
    for (int ot = 0; ot < 4; ++ot) {
        for (int i = t; i < 64 * H_; i += 256) {
            int o = i / H_, g = i % H_;
            Xc[o][g] = x[(((size_t)n * C_ + ot * 64 + o) * H_ + g) * W_ + w];
        }
        __syncthreads();
        float acc[4][6];
        #pragma unroll
        for (int i = 0; i < 4; ++i)
            #pragma unroll
            for (int j = 0; j < 6; ++j) acc[i][j] = 0.f;
        for (int g = 0; g < H_; ++g) {
            float xr[4], ar[6];
            #pragma unroll
            for (int i = 0; i < 4; ++i) xr[i] = Xc[to * 4 + i][g];
            #pragma unroll
            for (int j = 0; j < 6; ++j) ar[j] = A[th * 6 + j][g];
            #pragma unroll
            for (int i = 0; i < 4; ++i)
                #pragma unroll
                for (int j = 0; j < 6; ++j) acc[i][j] = fmaf(xr[i], ar[j], acc[i][j]);
        }
        #pragma unroll
        for (int i = 0; i < 4; ++i)
            #pragma unroll
            for (int j = 0; j < 6; ++j) {
                size_t ob = (((size_t)n * C_ + ot * 64 + to * 4 + i) * H_ + th * 6 + j) * W_ + w;
                out[ob] += acc[i][j];
            }
        __syncthreads();
    }
}

__global__ __launch_bounds__(256) void ccca_wv(
    const float* __restrict__ Wv, float* __restrict__ out)
{
    __shared__ float Ts[C_][64];
    int t = threadIdx.x;
    int n = blockIdx.x / 144;
    int p0 = (blockIdx.x % 144) * 64;
    float* base = out + (size_t)n * C_ * HW_ + p0;
    for (int i = t; i < C_ * 16; i += 256) {
        int o = i >> 4, p4 = (i & 15) << 2;
        *(float4*)&Ts[o][p4] = *(const float4*)(base + (size_t)o * HW_ + p4);
    }
    __syncthreads();
    int cb = t >> 4, pb = t & 15;
    float acc[16][4];
    #pragma unroll
    for (int j = 0; j < 16; ++j)
        #pragma unroll
        for (int p = 0; p < 4; ++p) acc[j][p] = 0.f;
    for (int o = 0; o < C_; o += 4) {
        float tvv[4][4];
        #pragma unroll
        for (int k = 0; k < 4; ++k) {
            float4 q = *(float4*)&Ts[o + k][pb * 4];
            tvv[k][0] = q.x; tvv[k][1] = q.y; tvv[k][2] = q.z; tvv[k][3] = q.w;
        }
        #pragma unroll
        for (int j = 0; j < 16; ++j) {
            float4 wv = *(const float4*)(Wv + (size_t)(cb * 16 + j) * C_ + o);
            float wvv[4] = {wv.x, wv.y, wv.z, wv.w};
            #pragma unroll
            for (int k = 0; k < 4; ++k)
                #pragma unroll
                for (int p = 0; p < 4; ++p)
                    acc[j][p] = fmaf(wvv[k], tvv[k][p], acc[j][p]);
        }
    }
    #pragma unroll
    for (int j = 0; j < 16; ++j) {
        float4 r; r.x = acc[j][0]; r.y = acc[j][1]; r.z = acc[j][2]; r.w = acc[j][3];
        *(float4*)(base + (size_t)(cb * 16 + j) * HW_ + pb * 4) = r;
    }
}

__global__ __launch_bounds__(256) void ccca_pool(
    const float* __restrict__ out, float* __restrict__ avg, float* __restrict__ mx)
{
    int nc = blockIdx.x;
    const float* p = out + (size_t)nc * HW_;
    int t = threadIdx.x;
    float s = 0.f, m = -1e30f;
    for (int i = t; i < HW_; i += 256) { float v = p[i]; s += v; m = fmaxf(m, v); }
    #pragma unroll
    for (int off = 32; off > 0; off >>= 1) {
        s += __shfl_down(s, off);
        m = fmaxf(m, __shfl_down(m, off));
    }
    __shared__ float ss[4], smx[4];
    int wv = t >> 6;
    if ((t & 63) == 0) { ss[wv] = s; smx[wv] = m; }
    __syncthreads();
    if (t == 0) {
        s = ss[0] + ss[1] + ss[2] + ss[3];
        m = fmaxf(fmaxf(smx[0], smx[1]), fmaxf(smx[2], smx[3]));
        avg[nc] = s * (1.f / 9216.f);
        mx[nc] = m;
    }
}

__global__ __launch_bounds__(256) void ccca_gate(
    const float* __restrict__ avg, const float* __restrict__ mx,
    const float* __restrict__ W1, const float* __restrict__ W2,
    float* __restrict__ gate)
{
    __shared__ float sa[C_], sm[C_], hs[C_];
    int n = blockIdx.x, t = threadIdx.x;
    sa[t] = avg[n * C_ + t];
    sm[t] = mx[n * C_ + t];
    __syncthreads();
    const float* w1r = W1 + (size_t)t * C_;
    float aa = 0.f, am = 0.f;
    for (int i = 0; i < C_; ++i) { float wv = w1r[i]; aa = fmaf(wv, sa[i], aa); am = fmaf(wv, sm[i], am); }
    hs[t] = fmaxf(aa, 0.f) + fmaxf(am, 0.f);
    __syncthreads();
    const float* w2r = W2 + (size_t)t * C_;
    float g = 0.f;
    for (int i = 0; i < C_; ++i) g = fmaf(w2r[i], hs[i], g);
    gate[n * C_ + t] = 1.f / (1.f + __expf(-g));
}

__global__ __launch_bounds__(256) void ccca_final(
    const float* __restrict__ x, const float* __restrict__ gate,
    const float* __restrict__ gama, float* __restrict__ out)
{
    float g0 = gama[0];
    const size_t total = (size_t)N_ * C_ * HW_ / 4;
    for (size_t i = (size_t)blockIdx.x * 256 + threadIdx.x; i < total; i += (size_t)gridDim.x * 256) {
        float4 o = ((const float4*)out)[i];
        float4 xv = ((const float4*)x)[i];
        size_t nc = (i * 4) / HW_;
        float sc = g0 * gate[nc];
        o.x = fmaf(sc, o.x, xv.x);
        o.y = fmaf(sc, o.y, xv.y);
        o.z = fmaf(sc, o.z, xv.z);
        o.w = fmaf(sc, o.w, xv.w);
        ((float4*)out)[i] = o;
    }
}

// ===========================================================================

extern "C" void kernel_launch(void* const* d_in, const int* in_sizes, int n_in,
                              void* d_out, int out_size, void* d_ws, size_t ws_size,
                              hipStream_t stream)
{
    const float* x    = (const float*)d_in[0];
    const float* Wq   = (const float*)d_in[1];
    const float* Wk   = (const float*)d_in[2];
    const float* Wv   = (const float*)d_in[3];
    const float* W1   = (const float*)d_in[4];
    const float* W2   = (const float*)d_in[5];
    const float* gama = (const float*)d_in[6];
    float* out = (float*)d_out;
    char*  ws  = (char*)d_ws;

    // ws layout (bytes):
    //   xP  @ 0           : 75,497,472   (fp16; reused as OPb by wvm)
    //   Tb  @ 75,497,472  : 75,497,472   (fp16; holds Qp/Kp partials before rowm
    //                                     fully overwrites it; reused as gate last)
    //   Qs  @ 150,994,944 :  2,359,296   (fp32; reused as psum)
    //   Ks  @ 153,354,240 :  2,359,296   (fp32; reused as pmax)
    //   Wvh @ 155,713,536 :    131,072   (fp16)
    const size_t WS_NEED3 = 155844608ull;

    if (ws_size >= WS_NEED3) {
        __half* xP   = (__half*)ws;
        __half* Tb   = (__half*)(ws + 75497472ull);
        float*  Qs   = (float*)(ws + 150994944ull);
        float*  Ks   = (float*)(ws + 153354240ull);
        __half* Wvh  = (__half*)(ws + 155713536ull);
        // Q/K partials live inside the (not-yet-written) Tb region:
        float*  Qp   = (float*)(ws + 75497472ull);                    // 8*QSZ_ floats
        float*  Kp   = (float*)(ws + 75497472ull + 8ull * QSZ_ * 4ull);
        float*  psum = Qs;
        float*  pmax = Ks;
        float*  gate = (float*)Tb;
        __half* OPb  = xP;

        ccca_qkt  <<<N_ * 96, 192, 0, stream>>>(x, Wq, Wk, xP, Qp, Kp);
        ccca_qkred<<<QSZ_ / 256, 256, 0, stream>>>(Qp, Kp, Qs, Ks);
        ccca_cvtwv<<<64, 256, 0, stream>>>(Wv, Wvh);
        ccca_rowm <<<N_ * H_, 256, 0, stream>>>(x, Qs, Ks, Tb);
        ccca_colm <<<N_ * W_, 256, 0, stream>>>(xP, Qs, Ks, Tb);
        ccca_wvm  <<<N_ * 144, 256, 0, stream>>>(Tb, Wvh, OPb, psum, pmax);
        ccca_gate2<<<N_, 256, 0, stream>>>(psum, pmax, W1, W2, gate);
        ccca_final2<<<2048, 256, 0, stream>>>(x, OPb, gate, gama, out);
    } else {
        float* wsf = (float*)ws;
        const size_t QSZ = (size_t)N_ * QK_ * HW_;
        float* Qb   = wsf;
        float* Kb   = wsf + QSZ;
        float* avg  = wsf + 2 * QSZ;
        float* mx   = avg + N_ * C_;
        float* gate = mx + N_ * C_;
        ccca_qk  <<<N_ * 36, 256, 0, stream>>>(x, Wq, Wk, Qb, Kb);
        ccca_row <<<N_ * H_, 256, 0, stream>>>(x, Qb, Kb, out);
        ccca_col <<<N_ * W_, 256, 0, stream>>>(x, Qb, Kb, out);
        ccca_wv  <<<N_ * 144, 256, 0, stream>>>(Wv, out);
        ccca_pool<<<N_ * C_, 256, 0, stream>>>(out, avg, mx);
        ccca_gate<<<N_, 256, 0, stream>>>(avg, mx, W1, W2, gate);
        ccca_final<<<2048, 256, 0, stream>>>(x, gate, gama, out);
    }
}

// Round 7
// 639.325 us; speedup vs baseline: 3.3404x; 1.0929x over previous
//
#include <hip/hip_runtime.h>
#include <hip/hip_fp16.h>

#define N_  16
#define C_  256
#define H_  96
#define W_  96
#define HW_ 9216
#define QK_ 4
#define QSZ_ 589824   // N_*QK_*HW_

struct alignas(8) h4 { __half2 a, b; };

__device__ inline void h4_unpack(h4 v, float* f) {
    float2 lo = __half22float2(v.a), hi = __half22float2(v.b);
    f[0] = lo.x; f[1] = lo.y; f[2] = hi.x; f[3] = hi.y;
}
__device__ inline h4 h4_pack(float a, float b, float c, float d) {
    h4 r; r.a = __floats2half2_rn(a, b); r.b = __floats2half2_rn(c, d); return r;
}

typedef __attribute__((ext_vector_type(8))) _Float16 f16x8;
typedef __attribute__((ext_vector_type(4))) float    f32x4;

// ===========================================================================
// FAST PATH
// ===========================================================================

// K0: PURE transpose x -> xP[n][g/8][w][c][g%8] fp16, LDS-staged so global
// stores are full-line (512B contiguous per w per wave-instr).
// Block = (n, gt, cc32). Grid 16*12*8 = 1536. Two passes of 16 c each.
// LDS row stride 132 elems + XOR swizzle (w ^ 4c) keeps both phases ~2-way.
__global__ __launch_bounds__(256) void ccca_qkt(
    const float* __restrict__ x, __half* __restrict__ xP)
{
    __shared__ __half L[128 * 132];   // 33,792 B
    int t = threadIdx.x;
    int blk = blockIdx.x;
    int n = blk / 96;
    int rem = blk % 96;
    int gt = rem / 8, cc = rem % 8;
    __half* xpb = xP + ((size_t)n * 12 + gt) * W_ * 2048;
    #pragma unroll
    for (int pass = 0; pass < 2; ++pass) {
        int cb = cc * 32 + pass * 16;
        if (pass) __syncthreads();
        // stage: 128 rows (16c x 8g) x 96 w, coalesced float4 reads
        for (int i = t; i < 128 * 24; i += 256) {
            int row = i / 24, j = i % 24;
            int c = row >> 3;
            int g = row & 7;
            int w0 = j * 4;
            float4 v = *(const float4*)(x +
                ((size_t)(n * C_ + cb + c) * H_ + (gt * 8 + g)) * (size_t)W_ + w0);
            *(h4*)&L[row * 132 + (w0 ^ (c << 2))] = h4_pack(v.x, v.y, v.z, v.w);
        }
        __syncthreads();
        // store: per w, 16c x 8g = 256B contiguous; 64 lanes cover 2 w's fully
        for (int i = t; i < 96 * 32; i += 256) {
            int w = i >> 5, piece = i & 31;
            int c = piece >> 1, g0 = (piece & 1) << 2;
            const __half* Lr = &L[(c * 8 + g0) * 132 + (w ^ (c << 2))];
            h4 o;
            o.a = __halves2half2(Lr[0],   Lr[132]);
            o.b = __halves2half2(Lr[264], Lr[396]);
            *(h4*)(xpb + (size_t)w * 2048 + (cb + c) * 8 + g0) = o;
        }
    }
}

// K1: per (n,h): stage x row -> Q,K (in-LDS, also persisted) -> scores ->
// softmax -> T1 via MFMA. Writes Tb[n][px][c] fp16 + Qs/Ks global.
__global__ __launch_bounds__(256) void ccca_rowm(
    const float* __restrict__ x, const float* __restrict__ Wq, const float* __restrict__ Wk,
    float* __restrict__ Qs, float* __restrict__ Ks, __half* __restrict__ Tb)
{
    __shared__ __half Xs[C_][104];     // [c][v]
    __shared__ __half A1[W_][104];     // [w][v]; front 8KB doubles as sW before scores
    __shared__ float sQ[QK_][W_], sK[QK_][W_];
    float* sW = (float*)&A1[0][0];     // 8x256 fp32 = 8KB (A1 region is 19.9KB)
    int t = threadIdx.x;
    int n = blockIdx.x / H_, h = blockIdx.x % H_;
    const float* xb = x + (size_t)n * C_ * HW_ + (size_t)h * W_;
    for (int i = t; i < C_ * 24; i += 256) {
        int c = i / 24, v4 = (i % 24) * 4;
        float4 v = *(const float4*)(xb + (size_t)c * HW_ + v4);
        *(h4*)&Xs[c][v4] = h4_pack(v.x, v.y, v.z, v.w);
    }
    for (int i = t; i < 512; i += 256) {   // Wq (256 f4) then Wk (256 f4)
        float4 v = (i < 256) ? ((const float4*)Wq)[i] : ((const float4*)Wk)[i - 256];
        ((float4*)sW)[i] = v;
    }
    __syncthreads();
    // Q/K projection from LDS tile (lane-consecutive Xs reads, conflict-free)
    if (t < 192) {
        int w = t % 96, sel = t / 96;
        float acc[4] = {0.f, 0.f, 0.f, 0.f};
        const float* wr = sW + sel * 4 * C_;
        for (int c = 0; c < C_; ++c) {
            float xv = __half2float(Xs[c][w]);
            #pragma unroll
            for (int q = 0; q < 4; ++q)
                acc[q] = fmaf(wr[q * C_ + c], xv, acc[q]);
        }
        #pragma unroll
        for (int q = 0; q < 4; ++q) {
            size_t off = (((size_t)n * QK_ + q) * H_ + h) * W_ + w;
            if (sel) { sK[q][w] = acc[q]; Ks[off] = acc[q]; }
            else     { sQ[q][w] = acc[q]; Qs[off] = acc[q]; }
        }
    }
    __syncthreads();
    for (int i = t; i < W_ * W_; i += 256) {   // overwrites sW region (dead now)
        int w = i / W_, v = i % W_;
        float s = 0.f;
        #pragma unroll
        for (int q = 0; q < QK_; ++q) s = fmaf(sQ[q][w], sK[q][v], s);
        A1[w][v] = __float2half(s);
    }
    __syncthreads();
    if (t < W_) {
        float m = -1e30f;
        for (int v = 0; v < W_; ++v) m = fmaxf(m, __half2float(A1[t][v]));
        float sum = 0.f;
        for (int v = 0; v < W_; ++v) {
            float e = __expf(__half2float(A1[t][v]) - m);
            sum += e; A1[t][v] = __float2half(e);
        }
        float inv = 1.f / sum;
        for (int v = 0; v < W_; ++v)
            A1[t][v] = __float2half(__half2float(A1[t][v]) * inv);
    }
    __syncthreads();
    int wd = t >> 6, lane = t & 63, ln15 = lane & 15, kg = lane >> 4;
    f32x4 acc[4][6];
    #pragma unroll
    for (int i = 0; i < 4; ++i)
        #pragma unroll
        for (int p = 0; p < 6; ++p) acc[i][p] = (f32x4){0.f, 0.f, 0.f, 0.f};
    #pragma unroll
    for (int kk = 0; kk < 3; ++kk) {
        f16x8 a[4], b[6];
        #pragma unroll
        for (int i = 0; i < 4; ++i)
            a[i] = *(const f16x8*)&Xs[64 * wd + 16 * i + ln15][kk * 32 + kg * 8];
        #pragma unroll
        for (int p = 0; p < 6; ++p)
            b[p] = *(const f16x8*)&A1[16 * p + ln15][kk * 32 + kg * 8];
        #pragma unroll
        for (int i = 0; i < 4; ++i)
            #pragma unroll
            for (int p = 0; p < 6; ++p)
                acc[i][p] = __builtin_amdgcn_mfma_f32_16x16x32_f16(a[i], b[p], acc[i][p], 0, 0, 0);
    }
    __half* Tn = Tb + ((size_t)n * H_ + h) * W_ * C_;
    #pragma unroll
    for (int i = 0; i < 4; ++i) {
        int c0 = 64 * wd + 16 * i + 4 * kg;
        #pragma unroll
        for (int p = 0; p < 6; ++p) {
            int w = 16 * p + ln15;
            *(h4*)(Tn + (size_t)w * C_ + c0) =
                h4_pack(acc[i][p][0], acc[i][p][1], acc[i][p][2], acc[i][p][3]);
        }
    }
}

// K2: per (n,w): col scores+softmax, T2 via MFMA, RMW into Tb.
__global__ __launch_bounds__(256) void ccca_colm(
    const __half* __restrict__ xP, const float* __restrict__ Qs, const float* __restrict__ Ks,
    __half* __restrict__ Tb)
{
    __shared__ __half Xs[C_][104];     // [c][g]
    __shared__ __half A2[H_][104];     // [h][g]
    __shared__ float sQ[QK_][H_], sK[QK_][H_];
    int t = threadIdx.x;
    int n = blockIdx.x / W_, w = blockIdx.x % W_;
    for (int i = t; i < 12 * C_; i += 256) {
        int gb = i >> 8, c = i & 255;
        f16x8 v = *(const f16x8*)(xP + (((size_t)n * 12 + gb) * W_ + w) * 2048 + (size_t)c * 8);
        *(f16x8*)&Xs[c][gb * 8] = v;
    }
    for (int i = t; i < 2 * QK_ * H_; i += 256) {
        int sel = i / (QK_ * H_), r = i % (QK_ * H_);
        int q = r / H_, g = r % H_;
        float v = (sel ? Ks : Qs)[(((size_t)n * QK_ + q) * H_ + g) * W_ + w];
        if (sel) sK[q][g] = v; else sQ[q][g] = v;
    }
    __syncthreads();
    for (int i = t; i < H_ * H_; i += 256) {
        int hh = i / H_, g = i % H_;
        float s = 0.f;
        #pragma unroll
        for (int q = 0; q < QK_; ++q) s = fmaf(sQ[q][hh], sK[q][g], s);
        A2[hh][g] = __float2half(s);
    }
    __syncthreads();
    if (t < H_) {
        float m = -1e30f;
        for (int g = 0; g < H_; ++g) m = fmaxf(m, __half2float(A2[t][g]));
        float sum = 0.f;
        for (int g = 0; g < H_; ++g) {
            float e = __expf(__half2float(A2[t][g]) - m);
            sum += e; A2[t][g] = __float2half(e);
        }
        float inv = 1.f / sum;
        for (int g = 0; g < H_; ++g)
            A2[t][g] = __float2half(__half2float(A2[t][g]) * inv);
    }
    __syncthreads();
    int wd = t >> 6, lane = t & 63, ln15 = lane & 15, kg = lane >> 4;
    f32x4 acc[6][4];
    #pragma unroll
    for (int i = 0; i < 6; ++i)
        #pragma unroll
        for (int p = 0; p < 4; ++p) acc[i][p] = (f32x4){0.f, 0.f, 0.f, 0.f};
    #pragma unroll
    for (int kk = 0; kk < 3; ++kk) {
        f16x8 a[6], b[4];
        #pragma unroll
        for (int i = 0; i < 6; ++i)
            a[i] = *(const f16x8*)&A2[16 * i + ln15][kk * 32 + kg * 8];
        #pragma unroll
        for (int p = 0; p < 4; ++p)
            b[p] = *(const f16x8*)&Xs[64 * wd + 16 * p + ln15][kk * 32 + kg * 8];
        #pragma unroll
        for (int i = 0; i < 6; ++i)
            #pragma unroll
            for (int p = 0; p < 4; ++p)
                acc[i][p] = __builtin_amdgcn_mfma_f32_16x16x32_f16(a[i], b[p], acc[i][p], 0, 0, 0);
    }
    __half* Tn = Tb + (size_t)n * HW_ * C_;
    #pragma unroll
    for (int i = 0; i < 6; ++i)
        #pragma unroll
        for (int p = 0; p < 4; ++p) {
            int c = 64 * wd + 16 * p + ln15;
            #pragma unroll
            for (int r = 0; r < 4; ++r) {
                int hh = 16 * i + 4 * kg + r;
                __half* ptr = Tn + ((size_t)hh * W_ + w) * C_ + c;
                *ptr = __float2half(__half2float(*ptr) + acc[i][p][r]);
            }
        }
}

// K2.5: convert Wv fp32 -> fp16
__global__ __launch_bounds__(256) void ccca_cvtwv(
    const float* __restrict__ Wv, __half* __restrict__ Wvh)
{
    int gid = blockIdx.x * 256 + threadIdx.x;
    float4 v = ((const float4*)Wv)[gid];
    ((h4*)Wvh)[gid] = h4_pack(v.x, v.y, v.z, v.w);
}

// K3 (MFMA): OPb[n][c][px] = sum_o Wvh[c][o] * Tb[n][px][o]; fused partial pools.
__global__ __launch_bounds__(256) void ccca_wvm(
    const __half* __restrict__ Tb, const __half* __restrict__ Wvh,
    __half* __restrict__ OPb, float* __restrict__ psum, float* __restrict__ pmax)
{
    int t = threadIdx.x;
    int wd = t >> 6, lane = t & 63;
    int ln15 = lane & 15, kg = lane >> 4;
    int n = blockIdx.x / 144, tile = blockIdx.x % 144;

    const _Float16* Ab = (const _Float16*)Wvh + (size_t)(64 * wd + ln15) * C_ + kg * 8;
    const _Float16* Bb = (const _Float16*)Tb +
                         ((size_t)n * HW_ + tile * 64 + ln15) * C_ + kg * 8;

    f32x4 acc[4][4];
    #pragma unroll
    for (int i = 0; i < 4; ++i)
        #pragma unroll
        for (int p = 0; p < 4; ++p) acc[i][p] = (f32x4){0.f, 0.f, 0.f, 0.f};

    #pragma unroll
    for (int kk = 0; kk < 8; ++kk) {
        f16x8 a[4], b[4];
        #pragma unroll
        for (int i = 0; i < 4; ++i)
            a[i] = *(const f16x8*)(Ab + (size_t)i * 16 * C_ + kk * 32);
        #pragma unroll
        for (int p = 0; p < 4; ++p)
            b[p] = *(const f16x8*)(Bb + (size_t)p * 16 * C_ + kk * 32);
        #pragma unroll
        for (int i = 0; i < 4; ++i)
            #pragma unroll
            for (int p = 0; p < 4; ++p)
                acc[i][p] = __builtin_amdgcn_mfma_f32_16x16x32_f16(a[i], b[p], acc[i][p], 0, 0, 0);
    }

    __half* dst = OPb + (size_t)n * C_ * HW_;
    #pragma unroll
    for (int i = 0; i < 4; ++i) {
        #pragma unroll
        for (int r = 0; r < 4; ++r) {
            int c = 64 * wd + 16 * i + 4 * kg + r;
            #pragma unroll
            for (int p = 0; p < 4; ++p) {
                int px = tile * 64 + 16 * p + ln15;
                dst[(size_t)c * HW_ + px] = __float2half(acc[i][p][r]);
            }
        }
    }

    #pragma unroll
    for (int i = 0; i < 4; ++i) {
        float ps[4] = {0.f, 0.f, 0.f, 0.f};
        float pm[4] = {-1e30f, -1e30f, -1e30f, -1e30f};
        #pragma unroll
        for (int p = 0; p < 4; ++p)
            #pragma unroll
            for (int r = 0; r < 4; ++r) {
                ps[r] += acc[i][p][r];
                pm[r] = fmaxf(pm[r], acc[i][p][r]);
            }
        #pragma unroll
        for (int m = 1; m <= 8; m <<= 1)
            #pragma unroll
            for (int r = 0; r < 4; ++r) {
                ps[r] += __shfl_xor(ps[r], m);
                pm[r] = fmaxf(pm[r], __shfl_xor(pm[r], m));
            }
        if (ln15 == 0) {
            size_t base = ((size_t)n * 144 + tile) * C_ + 64 * wd + 16 * i + 4 * kg;
            #pragma unroll
            for (int r = 0; r < 4; ++r) { psum[base + r] = ps[r]; pmax[base + r] = pm[r]; }
        }
    }
}

// K4: reduce partials + SE MLP -> gate[n][c]
__global__ __launch_bounds__(256) void ccca_gate2(
    const float* __restrict__ psum, const float* __restrict__ pmax,
    const float* __restrict__ W1, const float* __restrict__ W2,
    float* __restrict__ gate)
{
    __shared__ float sa[C_], sm[C_], hs[C_];
    int n = blockIdx.x, t = threadIdx.x;
    float s = 0.f, m = -1e30f;
    for (int i = 0; i < 144; ++i) {
        s += psum[((size_t)n * 144 + i) * C_ + t];
        m = fmaxf(m, pmax[((size_t)n * 144 + i) * C_ + t]);
    }
    sa[t] = s * (1.f / 9216.f);
    sm[t] = m;
    __syncthreads();
    const float* w1r = W1 + (size_t)t * C_;
    float aa = 0.f, am = 0.f;
    for (int i = 0; i < C_; ++i) { float wv = w1r[i]; aa = fmaf(wv, sa[i], aa); am = fmaf(wv, sm[i], am); }
    hs[t] = fmaxf(aa, 0.f) + fmaxf(am, 0.f);
    __syncthreads();
    const float* w2r = W2 + (size_t)t * C_;
    float g = 0.f;
    for (int i = 0; i < C_; ++i) g = fmaf(w2r[i], hs[i], g);
    gate[n * C_ + t] = 1.f / (1.f + __expf(-g));
}

// K5: out = x + gama*gate*out_pre (elementwise)
__global__ __launch_bounds__(256) void ccca_final2(
    const float* __restrict__ x, const __half* __restrict__ OPb,
    const float* __restrict__ gate, const float* __restrict__ gama,
    float* __restrict__ out)
{
    float g0 = gama[0];
    const size_t total = (size_t)N_ * C_ * HW_ / 4;
    for (size_t i = (size_t)blockIdx.x * 256 + threadIdx.x; i < total; i += (size_t)gridDim.x * 256) {
        float4 xv = ((const float4*)x)[i];
        float ov[4];
        h4_unpack(((const h4*)OPb)[i], ov);
        size_t nc = (i * 4) / HW_;
        float sc = g0 * gate[nc];
        float4 r;
        r.x = fmaf(sc, ov[0], xv.x);
        r.y = fmaf(sc, ov[1], xv.y);
        r.z = fmaf(sc, ov[2], xv.z);
        r.w = fmaf(sc, ov[3], xv.w);
        ((float4*)out)[i] = r;
    }
}

// ===========================================================================
// FALLBACK PATH (round-1 kernels, proven correct; runs only if ws too small)
// ===========================================================================

__global__ __launch_bounds__(256) void ccca_qk(
    const float* __restrict__ x, const float* __restrict__ Wq,
    const float* __restrict__ Wk, float* __restrict__ Qo, float* __restrict__ Ko)
{
    __shared__ float sWq[QK_ * C_];
    __shared__ float sWk[QK_ * C_];
    int t = threadIdx.x;
    for (int i = t; i < QK_ * C_; i += 256) { sWq[i] = Wq[i]; sWk[i] = Wk[i]; }
    __syncthreads();
    int n = blockIdx.x / 36;
    int p = (blockIdx.x % 36) * 256 + t;
    const float* xp = x + (size_t)n * C_ * HW_ + p;
    float qa[QK_] = {0.f, 0.f, 0.f, 0.f};
    float ka[QK_] = {0.f, 0.f, 0.f, 0.f};
    for (int c = 0; c < C_; ++c) {
        float v = xp[(size_t)c * HW_];
        #pragma unroll
        for (int q = 0; q < QK_; ++q) {
            qa[q] = fmaf(v, sWq[q * C_ + c], qa[q]);
            ka[q] = fmaf(v, sWk[q * C_ + c], ka[q]);
        }
    }
    size_t base = (size_t)n * QK_ * HW_ + p;
    #pragma unroll
    for (int q = 0; q < QK_; ++q) { Qo[base + q * HW_] = qa[q]; Ko[base + q * HW_] = ka[q]; }
}

__global__ __launch_bounds__(256) void ccca_row(
    const float* __restrict__ x, const float* __restrict__ Qw,
    const float* __restrict__ Kw, float* __restrict__ out)
{
    __shared__ float sQ[QK_][W_];
    __shared__ float sK[QK_][W_];
    __shared__ float A[W_][W_ + 1];
    __shared__ float Xs[64][W_ + 1];
    int t = threadIdx.x;
    int n = blockIdx.x / H_;
    int h = blockIdx.x % H_;
    for (int i = t; i < QK_ * W_; i += 256) {
        int q = i / W_, w = i % W_;
        size_t off = ((size_t)n * QK_ + q) * HW_ + h * W_ + w;
        sQ[q][w] = Qw[off];
        sK[q][w] = Kw[off];
    }
    __syncthreads();
    for (int i = t; i < W_ * W_; i += 256) {
        int w = i / W_, v = i % W_;
        float s = 0.f;
        #pragma unroll
        for (int q = 0; q < QK_; ++q) s = fmaf(sQ[q][w], sK[q][v], s);
        A[w][v] = s;
    }
    __syncthreads();
    if (t < W_) {
        float m = -1e30f;
        for (int v = 0; v < W_; ++v) m = fmaxf(m, A[t][v]);
        float sum = 0.f;
        for (int v = 0; v < W_; ++v) { float e = __expf(A[t][v] - m); A[t][v] = e; sum += e; }
        float inv = 1.f / sum;
        for (int v = 0; v < W_; ++v) A[t][v] *= inv;
    }
    __syncthreads();
    int to = t >> 4, tw = t & 15;
    for (int ot = 0; ot < 4; ++ot) {
        for (int i = t; i < 64 * W_ / 4; i += 256) {
            int f = i * 4;
            int o = f / W_, v = f % W_;
            float4 val = *(const float4*)(x + (((size_t)n * C_ + ot * 64 + o) * H_ + h) * W_ + v);
            Xs[o][v] = val.x; Xs[o][v + 1] = val.y; Xs[o][v + 2] = val.z; Xs[o][v + 3] = val.w;
        }
        __syncthreads();
        float acc[4][6];
        #pragma unroll
        for (int i = 0; i < 4; ++i)
            #pragma unroll
            for (int j = 0; j < 6; ++j) acc[i][j] = 0.f;
        for (int v = 0; v < W_; ++v) {
            float xr[4], ar[6];
            #pragma unroll
            for (int i = 0; i < 4; ++i) xr[i] = Xs[to * 4 + i][v];
            #pragma unroll
            for (int j = 0; j < 6; ++j) ar[j] = A[tw * 6 + j][v];
            #pragma unroll
            for (int i = 0; i < 4; ++i)
                #pragma unroll
                for (int j = 0; j < 6; ++j) acc[i][j] = fmaf(xr[i], ar[j], acc[i][j]);
        }
        #pragma unroll
        for (int i = 0; i < 4; ++i) {
            size_t ob = (((size_t)n * C_ + ot * 64 + to * 4 + i) * H_ + h) * W_ + tw * 6;
            #pragma unroll
            for (int j = 0; j < 6; ++j) out[ob + j] = acc[i][j];
        }
        __syncthreads();
    }
}

__global__ __launch_bounds__(256) void ccca_col(
    const float* __restrict__ x, const float* __restrict__ Qw,
    const float* __restrict__ Kw, float* __restrict__ out)
{
    __shared__ float sQ[QK_][H_];
    __shared__ float sK[QK_][H_];
    __shared__ float A[H_][H_ + 1];
    __shared__ float Xc[64][H_ + 1];
    int t = threadIdx.x;
    int n = blockIdx.x / W_;
    int w = blockIdx.x % W_;
    for (int i = t; i < QK_ * H_; i += 256) {
        int q = i / H_, hh = i % H_;
        size_t off = ((size_t)n * QK_ + q) * HW_ + hh * W_ + w;
        sQ[q][hh] = Qw[off];
        sK[q][hh] = Kw[off];
    }
    __syncthreads();
    for (int i = t; i < H_ * H_; i += 256) {
        int hh = i / H_, g = i % H_;
        float s = 0.f;
        #pragma unroll
        for (int q = 0; q < QK_; ++q) s = fmaf(sQ[q][hh], sK[q][g], s);
        A[hh][g] = s;
    }
    __syncthreads();
    if (t < H_) {
        float m = -1e30f;
        for (int g = 0; g < H_; ++g) m = fmaxf(m, A[t][g]);
        float sum = 0.f;
        for (int g = 0; g < H_; ++g) { float e = __expf(A[t][g] - m); A[t][g] = e; sum += e; }
        float inv = 1.f / sum;
        for (int g = 0; g < H_; ++g) A[t][g] *= inv;
    }
    __syncthreads();
    int to = t >> 4, th = t & 15;
    for (int ot = 0; ot < 4; ++ot) {
        for (int i = t; i < 64 * H_; i += 256) {
            int o = i / H_, g = i % H_;
            Xc[o][g] = x[(((size_t)n * C_ + ot * 64 + o) * H_ + g) * W_ + w];
        }
        __syncthreads();
        float acc[4][6];
        #pragma unroll
        for (int i = 0; i < 4; ++i)
            #pragma unroll
            for (int j = 0; j < 6; ++j) acc[i][j] = 0.f;
        for (int g = 0; g < H_; ++g) {
            float xr[4], ar[6];
            #pragma unroll
            for (int i = 0; i < 4; ++i) xr[i] = Xc[to * 4 + i][g];
            #pragma unroll
            for (int j = 0; j < 6; ++j) ar[j] = A[th * 6 + j][g];
            #pragma unroll
            for (int i = 0; i < 4; ++i)
                #pragma unroll
                for (int j = 0; j < 6; ++j) acc[i][j] = fmaf(xr[i], ar[j], acc[i][j]);
        }
        #pragma unroll
        for (int i = 0; i < 4; ++i)
            #pragma unroll
            for (int j = 0; j < 6; ++j) {
                size_t ob = (((size_t)n * C_ + ot * 64 + to * 4 + i) * H_ + th * 6 + j) * W_ + w;
                out[ob] += acc[i][j];
            }
        __syncthreads();
    }
}

__global__ __launch_bounds__(256) void ccca_wv(
    const float* __restrict__ Wv, float* __restrict__ out)
{
    __shared__ float Ts[C_][64];
    int t = threadIdx.x;
    int n = blockIdx.x / 144;
    int p0 = (blockIdx.x % 144) * 64;
    float* base = out + (size_t)n * C_ * HW_ + p0;
    for (int i = t; i < C_ * 16; i += 256) {
        int o = i >> 4, p4 = (i & 15) << 2;
        *(float4*)&Ts[o][p4] = *(const float4*)(base + (size_t)o * HW_ + p4);
    }
    __syncthreads();
    int cb = t >> 4, pb = t & 15;
    float acc[16][4];
    #pragma unroll
    for (int j = 0; j < 16; ++j)
        #pragma unroll
        for (int p = 0; p < 4; ++p) acc[j][p] = 0.f;
    for (int o = 0; o < C_; o += 4) {
        float tvv[4][4];
        #pragma unroll
        for (int k = 0; k < 4; ++k) {
            float4 q = *(float4*)&Ts[o + k][pb * 4];
            tvv[k][0] = q.x; tvv[k][1] = q.y; tvv[k][2] = q.z; tvv[k][3] = q.w;
        }
        #pragma unroll
        for (int j = 0; j < 16; ++j) {
            float4 wv = *(const float4*)(Wv + (size_t)(cb * 16 + j) * C_ + o);
            float wvv[4] = {wv.x, wv.y, wv.z, wv.w};
            #pragma unroll
            for (int k = 0; k < 4; ++k)
                #pragma unroll
                for (int p = 0; p < 4; ++p)
                    acc[j][p] = fmaf(wvv[k], tvv[k][p], acc[j][p]);
        }
    }
    #pragma unroll
    for (int j = 0; j < 16; ++j) {
        float4 r; r.x = acc[j][0]; r.y = acc[j][1]; r.z = acc[j][2]; r.w = acc[j][3];
        *(float4*)(base + (size_t)(cb * 16 + j) * HW_ + pb * 4) = r;
    }
}

__global__ __launch_bounds__(256) void ccca_pool(
    const float* __restrict__ out, float* __restrict__ avg, float* __restrict__ mx)
{
    int nc = blockIdx.x;
    const float* p = out + (size_t)nc * HW_;
    int t = threadIdx.x;
    float s = 0.f, m = -1e30f;
    for (int i = t; i < HW_; i += 256) { float v = p[i]; s += v; m = fmaxf(m, v); }
    #pragma unroll
    for (int off = 32; off > 0; off >>= 1) {
        s += __shfl_down(s, off);
        m = fmaxf(m, __shfl_down(m, off));
    }
    __shared__ float ss[4], smx[4];
    int wv = t >> 6;
    if ((t & 63) == 0) { ss[wv] = s; smx[wv] = m; }
    __syncthreads();
    if (t == 0) {
        s = ss[0] + ss[1] + ss[2] + ss[3];
        m = fmaxf(fmaxf(smx[0], smx[1]), fmaxf(smx[2], smx[3]));
        avg[nc] = s * (1.f / 9216.f);
        mx[nc] = m;
    }
}

__global__ __launch_bounds__(256) void ccca_gate(
    const float* __restrict__ avg, const float* __restrict__ mx,
    const float* __restrict__ W1, const float* __restrict__ W2,
    float* __restrict__ gate)
{
    __shared__ float sa[C_], sm[C_], hs[C_];
    int n = blockIdx.x, t = threadIdx.x;
    sa[t] = avg[n * C_ + t];
    sm[t] = mx[n * C_ + t];
    __syncthreads();
    const float* w1r = W1 + (size_t)t * C_;
    float aa = 0.f, am = 0.f;
    for (int i = 0; i < C_; ++i) { float wv = w1r[i]; aa = fmaf(wv, sa[i], aa); am = fmaf(wv, sm[i], am); }
    hs[t] = fmaxf(aa, 0.f) + fmaxf(am, 0.f);
    __syncthreads();
    const float* w2r = W2 + (size_t)t * C_;
    float g = 0.f;
    for (int i = 0; i < C_; ++i) g = fmaf(w2r[i], hs[i], g);
    gate[n * C_ + t] = 1.f / (1.f + __expf(-g));
}

__global__ __launch_bounds__(256) void ccca_final(
    const float* __restrict__ x, const float* __restrict__ gate,
    const float* __restrict__ gama, float* __restrict__ out)
{
    float g0 = gama[0];
    const size_t total = (size_t)N_ * C_ * HW_ / 4;
    for (size_t i = (size_t)blockIdx.x * 256 + threadIdx.x; i < total; i += (size_t)gridDim.x * 256) {
        float4 o = ((const float4*)out)[i];
        float4 xv = ((const float4*)x)[i];
        size_t nc = (i * 4) / HW_;
        float sc = g0 * gate[nc];
        o.x = fmaf(sc, o.x, xv.x);
        o.y = fmaf(sc, o.y, xv.y);
        o.z = fmaf(sc, o.z, xv.z);
        o.w = fmaf(sc, o.w, xv.w);
        ((float4*)out)[i] = o;
    }
}

// ===========================================================================

extern "C" void kernel_launch(void* const* d_in, const int* in_sizes, int n_in,
                              void* d_out, int out_size, void* d_ws, size_t ws_size,
                              hipStream_t stream)
{
    const float* x    = (const float*)d_in[0];
    const float* Wq   = (const float*)d_in[1];
    const float* Wk   = (const float*)d_in[2];
    const float* Wv   = (const float*)d_in[3];
    const float* W1   = (const float*)d_in[4];
    const float* W2   = (const float*)d_in[5];
    const float* gama = (const float*)d_in[6];
    float* out = (float*)d_out;
    char*  ws  = (char*)d_ws;

    // ws layout (bytes):
    //   xP  @ 0           : 75,497,472   (fp16; reused as OPb by wvm)
    //   Tb  @ 75,497,472  : 75,497,472   (fp16; reused as gate after wvm)
    //   Qs  @ 150,994,944 :  2,359,296   (fp32; reused as psum)
    //   Ks  @ 153,354,240 :  2,359,296   (fp32; reused as pmax)
    //   Wvh @ 155,713,536 :    131,072   (fp16)
    const size_t WS_NEED3 = 155844608ull;

    if (ws_size >= WS_NEED3) {
        __half* xP   = (__half*)ws;
        __half* Tb   = (__half*)(ws + 75497472ull);
        float*  Qs   = (float*)(ws + 150994944ull);
        float*  Ks   = (float*)(ws + 153354240ull);
        __half* Wvh  = (__half*)(ws + 155713536ull);
        float*  psum = Qs;
        float*  pmax = Ks;
        float*  gate = (float*)Tb;
        __half* OPb  = xP;

        ccca_rowm <<<N_ * H_, 256, 0, stream>>>(x, Wq, Wk, Qs, Ks, Tb);
        ccca_qkt  <<<N_ * 96, 256, 0, stream>>>(x, xP);
        ccca_cvtwv<<<64, 256, 0, stream>>>(Wv, Wvh);
        ccca_colm <<<N_ * W_, 256, 0, stream>>>(xP, Qs, Ks, Tb);
        ccca_wvm  <<<N_ * 144, 256, 0, stream>>>(Tb, Wvh, OPb, psum, pmax);
        ccca_gate2<<<N_, 256, 0, stream>>>(psum, pmax, W1, W2, gate);
        ccca_final2<<<2048, 256, 0, stream>>>(x, OPb, gate, gama, out);
    } else {
        float* wsf = (float*)ws;
        const size_t QSZ = (size_t)N_ * QK_ * HW_;
        float* Qb   = wsf;
        float* Kb   = wsf + QSZ;
        float* avg  = wsf + 2 * QSZ;
        float* mx   = avg + N_ * C_;
        float* gate = mx + N_ * C_;
        ccca_qk  <<<N_ * 36, 256, 0, stream>>>(x, Wq, Wk, Qb, Kb);
        ccca_row <<<N_ * H_, 256, 0, stream>>>(x, Qb, Kb, out);
        ccca_col <<<N_ * W_, 256, 0, stream>>>(x, Qb, Kb, out);
        ccca_wv  <<<N_ * 144, 256, 0, stream>>>(Wv, out);
        ccca_pool<<<N_ * C_, 256, 0, stream>>>(out, avg, mx);
        ccca_gate<<<N_, 256, 0, stream>>>(avg, mx, W1, W2, gate);
        ccca_final<<<2048, 256, 0, stream>>>(x, gate, gama, out);
    }
}